// Round 3
// baseline (1316.792 us; speedup 1.0000x reference)
//
#include <hip/hip_runtime.h>
#include <math.h>

#define NN 100000
#define NE 1600000
#define HN 64
#define HE 16
#define LAYERS 3
#define NEG 0.2f
#define BN_EPS 1e-5f

#define SCAN_CHUNK 2048
#define NB_SCAN 49   // ceil(NN / SCAN_CHUNK)

// ---------------- K1: node encode (x @ fc_node_w + b) + BN batch stats ----------------
__global__ __launch_bounds__(256) void k_encode(const float* __restrict__ x,
    const float* __restrict__ w, const float* __restrict__ b,
    float* __restrict__ h, float* __restrict__ stat_sum, float* __restrict__ stat_sq)
{
    int wave = threadIdx.x >> 6;
    int c    = threadIdx.x & 63;
    int n0   = blockIdx.x * 32 + wave * 8;
    float w0 = w[c], w1 = w[64 + c], w2 = w[128 + c], bc = b[c];
    float ps = 0.f, pq = 0.f;
    #pragma unroll
    for (int i = 0; i < 8; i++) {
        int n = n0 + i;
        float x0 = x[n * 3], x1 = x[n * 3 + 1], x2 = x[n * 3 + 2];
        float v = fmaf(x0, w0, fmaf(x1, w1, fmaf(x2, w2, bc)));
        h[n * 64 + c] = v;
        ps += v; pq += v * v;
    }
    __shared__ float rs[4][64], rq[4][64];
    rs[wave][c] = ps; rq[wave][c] = pq;
    __syncthreads();
    if (wave == 0) {
        float S = rs[0][c] + rs[1][c] + rs[2][c] + rs[3][c];
        float Q = rq[0][c] + rq[1][c] + rq[2][c] + rq[3][c];
        atomicAdd(&stat_sum[c], S);
        atomicAdd(&stat_sq[c], Q);
    }
}

// ---------------- K2: finalize BN affine + per-layer edge constants u, c0 ----------------
__global__ void k_params(const float* __restrict__ stat_sum, const float* __restrict__ stat_sq,
    const float* __restrict__ gamma, const float* __restrict__ beta,
    const float* __restrict__ few, const float* __restrict__ feb,
    const float* __restrict__ attn_w, const float* __restrict__ attn_b,
    float* __restrict__ bn_scale, float* __restrict__ bn_shift,
    float* __restrict__ u, float* __restrict__ c0)
{
    int t = threadIdx.x;
    if (t < 64) {
        float mean = stat_sum[t] * (1.0f / NN);
        float var  = stat_sq[t] * (1.0f / NN) - mean * mean;
        float sc   = gamma[t] * rsqrtf(var + BN_EPS);
        bn_scale[t] = sc;
        bn_shift[t] = beta[t] - mean * sc;
    }
    if (t < 192) {
        int l = t >> 6, c = t & 63;
        float uu = 0.f, cc = 0.f;
        for (int j = 0; j < HE; j++) {
            float wv = attn_w[((l * 144) + 128 + j) * 64 + c];
            uu += few[j] * wv;
            cc += feb[j] * wv;
        }
        u[l * 64 + c]  = uu;
        c0[l * 64 + c] = cc + attn_b[l * 64 + c];
    }
}

// ---------------- K3: apply BN affine ----------------
__global__ __launch_bounds__(256) void k_bn(float* __restrict__ h,
    const float* __restrict__ sc, const float* __restrict__ sh)
{
    int i = blockIdx.x * 256 + threadIdx.x;   // grid sized exactly N*64/256
    int c = i & 63;
    h[i] = fmaf(h[i], sc[c], sh[c]);
}

// ---------------- K4: degree histogram over dst ----------------
__global__ __launch_bounds__(256) void k_hist(const int* __restrict__ ei, int* __restrict__ deg)
{
    int k = blockIdx.x * 256 + threadIdx.x;   // grid exact NE/256
    atomicAdd(&deg[ei[NE + k]], 1);
}

// ---------------- K5-K7: exclusive scan -> row_ptr ----------------
__global__ __launch_bounds__(256) void k_scan1(const int* __restrict__ deg,
    int* __restrict__ row_ptr, int* __restrict__ totals)
{
    __shared__ int lds[256];
    int t = threadIdx.x;
    int base = blockIdx.x * SCAN_CHUNK + t * 8;
    int v[8]; int sum = 0;
    #pragma unroll
    for (int i = 0; i < 8; i++) {
        int idx = base + i;
        int xv = (idx < NN) ? deg[idx] : 0;
        sum += xv; v[i] = sum;            // inclusive within thread
    }
    lds[t] = sum;
    __syncthreads();
    for (int off = 1; off < 256; off <<= 1) {
        int xv = (t >= off) ? lds[t - off] : 0;
        __syncthreads();
        lds[t] += xv;
        __syncthreads();
    }
    int excl = lds[t] - sum;
    #pragma unroll
    for (int i = 0; i < 8; i++) {
        int idx = base + i;
        if (idx < NN) row_ptr[idx + 1] = excl + v[i];
    }
    if (t == 255) totals[blockIdx.x] = lds[255];
}

__global__ void k_scan2(int* __restrict__ totals)
{
    __shared__ int lds[64];
    int t = threadIdx.x;
    int xv = (t < NB_SCAN) ? totals[t] : 0;
    lds[t] = xv;
    __syncthreads();
    for (int off = 1; off < 64; off <<= 1) {
        int y = (t >= off) ? lds[t - off] : 0;
        __syncthreads();
        lds[t] += y;
        __syncthreads();
    }
    if (t < NB_SCAN) totals[t] = lds[t] - xv;  // exclusive
}

__global__ __launch_bounds__(256) void k_scan3(int* __restrict__ row_ptr,
    const int* __restrict__ totals)
{
    int i = blockIdx.x * 256 + threadIdx.x;
    if (i == 0) row_ptr[0] = 0;
    if (i < NN) {
        int b = i >> 11;
        if (b > 0) row_ptr[i + 1] += totals[b];
    }
}

// ---------------- K8: scatter edges into CSR (by dst) ----------------
__global__ __launch_bounds__(256) void k_scatter(const int* __restrict__ ei,
    const float* __restrict__ ea, const int* __restrict__ row_ptr,
    int* __restrict__ cnt, int* __restrict__ csrc, float* __restrict__ cea)
{
    int k = blockIdx.x * 256 + threadIdx.x;   // grid exact NE/256
    int d = ei[NE + k];
    int pos = atomicAdd(&cnt[d], 1);
    int j = row_ptr[d] + pos;
    csrc[j] = ei[k];
    cea[j]  = ea[k];
}

// ---------------- K9: per-node transforms: hl = h@W+b ; ai = hl@Wi ; aj = hl@Wj ----------------
__global__ __launch_bounds__(256) void k_transform(const float* __restrict__ h,
    const float* __restrict__ fcw, const float* __restrict__ fcb,
    const float* __restrict__ aw,
    float* __restrict__ hl, float* __restrict__ ai, float* __restrict__ aj, int l)
{
    __shared__ float sh[4][64], shl[4][64];
    int w = threadIdx.x >> 6, c = threadIdx.x & 63;
    int n = blockIdx.x * 4 + w;               // grid exact NN/4
    sh[w][c] = h[n * 64 + c];
    __syncthreads();
    const float* __restrict__ W0 = fcw + l * 64 * 64;
    float acc = fcb[l * 64 + c];
    #pragma unroll 8
    for (int j = 0; j < 64; j++) acc = fmaf(sh[w][j], W0[j * 64 + c], acc);
    shl[w][c] = acc;
    __syncthreads();
    const float* __restrict__ Wi = aw + (l * 144) * 64;
    const float* __restrict__ Wj = aw + (l * 144 + 64) * 64;
    float a1 = 0.f, a2 = 0.f;
    #pragma unroll 8
    for (int j = 0; j < 64; j++) {
        float hj = shl[w][j];
        a1 = fmaf(hj, Wi[j * 64 + c], a1);
        a2 = fmaf(hj, Wj[j * 64 + c], a2);
    }
    int o = n * 64 + c;
    hl[o] = acc; ai[o] = a1; aj[o] = a2;
}

// ---------------- K10: fused online-softmax attention aggregate (wave per dst node) ----------------
__global__ __launch_bounds__(256) void k_edge(const float* __restrict__ hl,
    const float* __restrict__ ai, const float* __restrict__ aj,
    const int* __restrict__ row_ptr, const int* __restrict__ csrc,
    const float* __restrict__ cea, const float* __restrict__ u, const float* __restrict__ c0,
    float* __restrict__ hout, int l)
{
    int w = threadIdx.x >> 6, c = threadIdx.x & 63;
    int n = blockIdx.x * 4 + w;               // grid exact NN/4
    int beg = row_ptr[n], end = row_ptr[n + 1];
    float aic = ai[n * 64 + c];
    float uc = u[l * 64 + c], c0c = c0[l * 64 + c];
    float m = -INFINITY, d = 0.f, s = 0.f;
    for (int k = beg; k < end; k++) {
        int sidx = csrc[k];
        float a = fmaf(cea[k], uc, aic + aj[sidx * 64 + c] + c0c);
        a = a > 0.f ? a : NEG * a;
        float mn = fmaxf(m, a);
        float corr = __expf(m - mn);
        float p = __expf(a - mn);
        d = fmaf(d, corr, p);
        s = fmaf(s, corr, p * hl[sidx * 64 + c]);
        m = mn;
    }
    hout[n * 64 + c] = s / (d + 1e-16f);
}

// ---------------- launch ----------------
extern "C" void kernel_launch(void* const* d_in, const int* in_sizes, int n_in,
                              void* d_out, int out_size, void* d_ws, size_t ws_size,
                              hipStream_t stream)
{
    const float* x    = (const float*)d_in[0];
    const float* ea   = (const float*)d_in[1];
    const int*   ei   = (const int*)d_in[2];
    const float* fnw  = (const float*)d_in[3];
    const float* fnb  = (const float*)d_in[4];
    const float* few  = (const float*)d_in[5];
    const float* feb  = (const float*)d_in[6];
    const float* gmm  = (const float*)d_in[7];
    const float* beta = (const float*)d_in[8];
    const float* fcw  = (const float*)d_in[9];
    const float* fcb  = (const float*)d_in[10];
    const float* aw   = (const float*)d_in[11];
    const float* ab   = (const float*)d_in[12];
    float* out = (float*)d_out;

    char* ws = (char*)d_ws;
    size_t off = 0;
    auto alloc = [&](size_t bytes) -> void* {
        void* p = ws + off;
        off += (bytes + 255) / 256 * 256;
        return p;
    };
    float* h       = (float*)alloc((size_t)NN * 64 * 4);
    float* hl      = (float*)alloc((size_t)NN * 64 * 4);
    float* ai      = (float*)alloc((size_t)NN * 64 * 4);
    float* aj      = (float*)alloc((size_t)NN * 64 * 4);
    int*   csrc    = (int*)  alloc((size_t)NE * 4);
    float* cea     = (float*)alloc((size_t)NE * 4);
    int*   row_ptr = (int*)  alloc((size_t)(NN + 1) * 4);
    int*   deg     = (int*)  alloc((size_t)NN * 4);      // deg + cnt contiguous: zero together
    int*   cnt     = (int*)  alloc((size_t)NN * 4);
    int*   totals  = (int*)  alloc(64 * 4);
    float* ssum    = (float*)alloc(64 * 4);              // ssum + ssq contiguous: zero together
    float* ssq     = (float*)alloc(64 * 4);
    float* bscale  = (float*)alloc(64 * 4);
    float* bshift  = (float*)alloc(64 * 4);
    float* uvec    = (float*)alloc(192 * 4);
    float* c0vec   = (float*)alloc(192 * 4);

    hipMemsetAsync(deg, 0, 2 * (size_t)NN * 4 + 256, stream);   // deg + cnt (+pad)
    hipMemsetAsync(ssum, 0, 2 * 64 * 4 + 256, stream);          // ssum + ssq (+pad)

    // encode + BN
    k_encode<<<NN / 32, 256, 0, stream>>>(x, fnw, fnb, h, ssum, ssq);
    k_params<<<1, 256, 0, stream>>>(ssum, ssq, gmm, beta, few, feb, aw, ab,
                                    bscale, bshift, uvec, c0vec);
    k_bn<<<NN * 64 / 256, 256, 0, stream>>>(h, bscale, bshift);

    // CSR build
    k_hist<<<NE / 256, 256, 0, stream>>>(ei, deg);
    k_scan1<<<NB_SCAN, 256, 0, stream>>>(deg, row_ptr, totals);
    k_scan2<<<1, 64, 0, stream>>>(totals);
    k_scan3<<<(NN + 255) / 256, 256, 0, stream>>>(row_ptr, totals);
    k_scatter<<<NE / 256, 256, 0, stream>>>(ei, ea, row_ptr, cnt, csrc, cea);

    // 3 GAT layers
    for (int l = 0; l < LAYERS; l++) {
        k_transform<<<NN / 4, 256, 0, stream>>>(h, fcw, fcb, aw, hl, ai, aj, l);
        float* ho = (l == LAYERS - 1) ? out : h;
        k_edge<<<NN / 4, 256, 0, stream>>>(hl, ai, aj, row_ptr, csrc, cea,
                                           uvec, c0vec, ho, l);
    }
    (void)in_sizes; (void)n_in; (void)out_size; (void)ws_size; (void)ab;
}

// Round 4
// 959.510 us; speedup vs baseline: 1.3724x; 1.3724x over previous
//
#include <hip/hip_runtime.h>
#include <math.h>

#define NN 100000
#define NE 1600000
#define LAYERS 3
#define NEG 0.2f
#define BN_EPS 1e-5f

#define SCAN_CHUNK 2048
#define NB_SCAN 49   // ceil(NN / SCAN_CHUNK)

typedef __attribute__((ext_vector_type(8))) short bf16x8;
typedef __attribute__((ext_vector_type(4))) float f32x4;

__device__ __forceinline__ unsigned f2bf(float x) {   // fp32 -> bf16 bits, RNE
    unsigned u = __float_as_uint(x);
    return (u + 0x7fffu + ((u >> 16) & 1u)) >> 16;
}

// ---------------- K1: node encode (x @ fc_node_w + b) + BN batch stats ----------------
__global__ __launch_bounds__(256) void k_encode(const float* __restrict__ x,
    const float* __restrict__ w, const float* __restrict__ b,
    float* __restrict__ h, float* __restrict__ stat_sum, float* __restrict__ stat_sq)
{
    int wave = threadIdx.x >> 6;
    int c    = threadIdx.x & 63;
    int n0   = blockIdx.x * 32 + wave * 8;
    float w0 = w[c], w1 = w[64 + c], w2 = w[128 + c], bc = b[c];
    float ps = 0.f, pq = 0.f;
    #pragma unroll
    for (int i = 0; i < 8; i++) {
        int n = n0 + i;
        float x0 = x[n * 3], x1 = x[n * 3 + 1], x2 = x[n * 3 + 2];
        float v = fmaf(x0, w0, fmaf(x1, w1, fmaf(x2, w2, bc)));
        h[n * 64 + c] = v;
        ps += v; pq += v * v;
    }
    __shared__ float rs[4][64], rq[4][64];
    rs[wave][c] = ps; rq[wave][c] = pq;
    __syncthreads();
    if (wave == 0) {
        float S = rs[0][c] + rs[1][c] + rs[2][c] + rs[3][c];
        float Q = rq[0][c] + rq[1][c] + rq[2][c] + rq[3][c];
        atomicAdd(&stat_sum[c], S);
        atomicAdd(&stat_sq[c], Q);
    }
}

// ---------------- K2: BN affine + per-layer edge constants u, c0 (with folded biases) ----------------
__global__ void k_params(const float* __restrict__ stat_sum, const float* __restrict__ stat_sq,
    const float* __restrict__ gamma, const float* __restrict__ beta,
    const float* __restrict__ few, const float* __restrict__ feb,
    const float* __restrict__ attn_w, const float* __restrict__ attn_b,
    const float* __restrict__ fcb,
    float* __restrict__ bn_scale, float* __restrict__ bn_shift,
    float* __restrict__ u, float* __restrict__ c0)
{
    int t = threadIdx.x;
    if (t < 64) {
        float mean = stat_sum[t] * (1.0f / NN);
        float var  = stat_sq[t] * (1.0f / NN) - mean * mean;
        float sc   = gamma[t] * rsqrtf(var + BN_EPS);
        bn_scale[t] = sc;
        bn_shift[t] = beta[t] - mean * sc;
    }
    if (t < 192) {
        int l = t >> 6, c = t & 63;
        const float* AW = attn_w + l * 144 * 64;
        float uu = 0.f, cc = 0.f;
        for (int j = 0; j < 16; j++) {
            float wv = AW[(128 + j) * 64 + c];
            uu = fmaf(few[j], wv, uu);
            cc = fmaf(feb[j], wv, cc);
        }
        // bias of xi/xj paths: fcb @ (Wi + Wj), folded into the per-channel constant
        float bi = 0.f;
        for (int tt = 0; tt < 64; tt++)
            bi = fmaf(fcb[l * 64 + tt], AW[tt * 64 + c] + AW[(64 + tt) * 64 + c], bi);
        u[t]  = uu;
        c0[t] = cc + attn_b[t] + bi;
    }
}

// ---------------- K2b: build transposed bf16 B-matrix [l][192 cols][64 k]:  [W0 | W0@Wi | W0@Wj] ----------------
__global__ __launch_bounds__(64) void k_prep(const float* __restrict__ fcw,
    const float* __restrict__ aw, unsigned short* __restrict__ wt)
{
    int g = blockIdx.x, l = blockIdx.y, k = threadIdx.x;
    const float* W0 = fcw + l * 4096;
    float v;
    if (g < 64) {
        v = W0[k * 64 + g];
    } else {
        int c = g & 63;
        const float* Wx = aw + l * 144 * 64 + (g < 128 ? 0 : 4096);
        float s = 0.f;
        for (int tt = 0; tt < 64; tt++) s = fmaf(W0[k * 64 + tt], Wx[tt * 64 + c], s);
        v = s;
    }
    wt[(l * 192 + g) * 64 + k] = (unsigned short)f2bf(v);
}

// ---------------- K3: apply BN affine ----------------
__global__ __launch_bounds__(256) void k_bn(float* __restrict__ h,
    const float* __restrict__ sc, const float* __restrict__ sh)
{
    int i = blockIdx.x * 256 + threadIdx.x;   // grid exact N*64/256
    int c = i & 63;
    h[i] = fmaf(h[i], sc[c], sh[c]);
}

// ---------------- K4: degree histogram over dst ----------------
__global__ __launch_bounds__(256) void k_hist(const int* __restrict__ ei, int* __restrict__ deg)
{
    int k = blockIdx.x * 256 + threadIdx.x;   // grid exact NE/256
    atomicAdd(&deg[ei[NE + k]], 1);
}

// ---------------- K5-K7: exclusive scan -> row_ptr ----------------
__global__ __launch_bounds__(256) void k_scan1(const int* __restrict__ deg,
    int* __restrict__ row_ptr, int* __restrict__ totals)
{
    __shared__ int lds[256];
    int t = threadIdx.x;
    int base = blockIdx.x * SCAN_CHUNK + t * 8;
    int v[8]; int sum = 0;
    #pragma unroll
    for (int i = 0; i < 8; i++) {
        int idx = base + i;
        int xv = (idx < NN) ? deg[idx] : 0;
        sum += xv; v[i] = sum;
    }
    lds[t] = sum;
    __syncthreads();
    for (int off = 1; off < 256; off <<= 1) {
        int xv = (t >= off) ? lds[t - off] : 0;
        __syncthreads();
        lds[t] += xv;
        __syncthreads();
    }
    int excl = lds[t] - sum;
    #pragma unroll
    for (int i = 0; i < 8; i++) {
        int idx = base + i;
        if (idx < NN) row_ptr[idx + 1] = excl + v[i];
    }
    if (t == 255) totals[blockIdx.x] = lds[255];
}

__global__ void k_scan2(int* __restrict__ totals)
{
    __shared__ int lds[64];
    int t = threadIdx.x;
    int xv = (t < NB_SCAN) ? totals[t] : 0;
    lds[t] = xv;
    __syncthreads();
    for (int off = 1; off < 64; off <<= 1) {
        int y = (t >= off) ? lds[t - off] : 0;
        __syncthreads();
        lds[t] += y;
        __syncthreads();
    }
    if (t < NB_SCAN) totals[t] = lds[t] - xv;
}

__global__ __launch_bounds__(256) void k_scan3(int* __restrict__ row_ptr,
    const int* __restrict__ totals)
{
    int i = blockIdx.x * 256 + threadIdx.x;
    if (i == 0) row_ptr[0] = 0;
    if (i < NN) {
        int b = i >> 11;
        if (b > 0) row_ptr[i + 1] += totals[b];
    }
}

// ---------------- K8: scatter edges into CSR (by dst) ----------------
__global__ __launch_bounds__(256) void k_scatter(const int* __restrict__ ei,
    const float* __restrict__ ea, const int* __restrict__ row_ptr,
    int* __restrict__ cnt, int* __restrict__ csrc, float* __restrict__ cea)
{
    int k = blockIdx.x * 256 + threadIdx.x;   // grid exact NE/256
    int d = ei[NE + k];
    int pos = atomicAdd(&cnt[d], 1);
    int j = row_ptr[d] + pos;
    csrc[j] = ei[k];
    cea[j]  = ea[k];
}

// ---------------- K9: MFMA transform: [hl | ai | aj] = h @ [W0 | Mi | Mj]  (bf16 MFMA) ----------------
// outputs: ai fp32; packed uint32 = {hi: bf16(aj), lo: bf16(hl)}
__global__ __launch_bounds__(256) void k_tf(const float* __restrict__ h,
    const unsigned short* __restrict__ wt_l, const float* __restrict__ fcb_l,
    float* __restrict__ ai, unsigned* __restrict__ packed)
{
    int tid = threadIdx.x;
    int wv = tid >> 6, l = tid & 63;
    int r16 = l & 15, quad = l >> 4;
    int n0 = blockIdx.x * 64 + wv * 16;           // wave's 16-node tile
    // ---- A fragments: row = l&15 (node), k = quad*8 + e (+32 per k-step), contiguous 8 bf16 ----
    int na = n0 + r16; if (na >= NN) na = NN - 1; // clamp (last block only)
    const float* hp = h + (size_t)na * 64 + quad * 8;
    bf16x8 a[2];
    #pragma unroll
    for (int ks = 0; ks < 2; ks++) {
        f32x4 lo = *(const f32x4*)(hp + ks * 32);
        f32x4 hi = *(const f32x4*)(hp + ks * 32 + 4);
        bf16x8 t;
        t[0] = (short)f2bf(lo[0]); t[1] = (short)f2bf(lo[1]);
        t[2] = (short)f2bf(lo[2]); t[3] = (short)f2bf(lo[3]);
        t[4] = (short)f2bf(hi[0]); t[5] = (short)f2bf(hi[1]);
        t[6] = (short)f2bf(hi[2]); t[7] = (short)f2bf(hi[3]);
        a[ks] = t;
    }
    // ---- 12 column-blocks of 16, K=64 in two MFMAs each ----
    f32x4 acc[12];
    #pragma unroll
    for (int i = 0; i < 12; i++) acc[i] = (f32x4){0.f, 0.f, 0.f, 0.f};
    const unsigned short* wb = wt_l + (size_t)r16 * 64 + quad * 8;  // B: col=l&15, k=quad*8+e
    #pragma unroll
    for (int cb = 0; cb < 12; cb++) {
        bf16x8 b0 = *(const bf16x8*)(wb + cb * 1024);        // (cb*16+r16)*64 + quad*8
        bf16x8 b1 = *(const bf16x8*)(wb + cb * 1024 + 32);   // + k-step 32
        acc[cb] = __builtin_amdgcn_mfma_f32_16x16x32_bf16(a[0], b0, acc[cb], 0, 0, 0);
        acc[cb] = __builtin_amdgcn_mfma_f32_16x16x32_bf16(a[1], b1, acc[cb], 0, 0, 0);
    }
    // ---- epilogue: D col = l&15, node = n0 + quad*4 + reg ----
    #pragma unroll
    for (int r = 0; r < 4; r++) {
        int nd = n0 + quad * 4 + r;
        if (nd < NN) {
            size_t base = (size_t)nd * 64 + r16;
            #pragma unroll
            for (int cq = 0; cq < 4; cq++) {
                float hlv = acc[cq][r] + fcb_l[cq * 16 + r16];
                float aiv = acc[4 + cq][r];
                float ajv = acc[8 + cq][r];
                ai[base + cq * 16]     = aiv;
                packed[base + cq * 16] = f2bf(hlv) | (f2bf(ajv) << 16);
            }
        }
    }
}

// ---------------- K10: fused softmax-attention aggregate (wave per dst node, no-max exp) ----------------
__global__ __launch_bounds__(256) void k_edge(const unsigned* __restrict__ packed,
    const float* __restrict__ ai, const int* __restrict__ row_ptr,
    const int* __restrict__ csrc, const float* __restrict__ cea,
    const float* __restrict__ u, const float* __restrict__ c0,
    float* __restrict__ hout, int l)
{
    int w = threadIdx.x >> 6, c = threadIdx.x & 63;
    int n = blockIdx.x * 4 + w;                   // grid exact NN/4
    int beg = row_ptr[n], end = row_ptr[n + 1];
    float base = ai[n * 64 + c] + c0[l * 64 + c];
    float uc = u[l * 64 + c];
    float d = 0.f, s = 0.f;
    for (int k = beg; k < end; k++) {
        int sidx = csrc[k];
        unsigned pk = packed[(size_t)sidx * 64 + c];
        float hlv = __uint_as_float(pk << 16);            // low16 = hl
        float ajv = __uint_as_float(pk & 0xffff0000u);    // high16 = aj
        float a = fmaf(cea[k], uc, base + ajv);
        a = a > 0.f ? a : NEG * a;
        float p = __expf(a);
        d += p;
        s = fmaf(p, hlv, s);
    }
    hout[n * 64 + c] = s / (d + 1e-16f);
}

// ---------------- launch ----------------
extern "C" void kernel_launch(void* const* d_in, const int* in_sizes, int n_in,
                              void* d_out, int out_size, void* d_ws, size_t ws_size,
                              hipStream_t stream)
{
    const float* x    = (const float*)d_in[0];
    const float* ea   = (const float*)d_in[1];
    const int*   ei   = (const int*)d_in[2];
    const float* fnw  = (const float*)d_in[3];
    const float* fnb  = (const float*)d_in[4];
    const float* few  = (const float*)d_in[5];
    const float* feb  = (const float*)d_in[6];
    const float* gmm  = (const float*)d_in[7];
    const float* beta = (const float*)d_in[8];
    const float* fcw  = (const float*)d_in[9];
    const float* fcb  = (const float*)d_in[10];
    const float* aw   = (const float*)d_in[11];
    const float* ab   = (const float*)d_in[12];
    float* out = (float*)d_out;

    char* ws = (char*)d_ws;
    size_t off = 0;
    auto alloc = [&](size_t bytes) -> void* {
        void* p = ws + off;
        off += (bytes + 255) / 256 * 256;
        return p;
    };
    float*    h       = (float*)   alloc((size_t)NN * 64 * 4);
    float*    ai      = (float*)   alloc((size_t)NN * 64 * 4);
    unsigned* packed  = (unsigned*)alloc((size_t)NN * 64 * 4);
    int*      csrc    = (int*)     alloc((size_t)NE * 4);
    float*    cea     = (float*)   alloc((size_t)NE * 4);
    int*      row_ptr = (int*)     alloc((size_t)(NN + 1) * 4);
    int*      deg     = (int*)     alloc((size_t)NN * 4);   // deg + cnt contiguous: zero together
    int*      cnt     = (int*)     alloc((size_t)NN * 4);
    int*      totals  = (int*)     alloc(64 * 4);
    float*    ssum    = (float*)   alloc(64 * 4);           // ssum + ssq contiguous: zero together
    float*    ssq     = (float*)   alloc(64 * 4);
    float*    bscale  = (float*)   alloc(64 * 4);
    float*    bshift  = (float*)   alloc(64 * 4);
    float*    uvec    = (float*)   alloc(192 * 4);
    float*    c0vec   = (float*)   alloc(192 * 4);
    unsigned short* wt = (unsigned short*)alloc((size_t)LAYERS * 192 * 64 * 2);

    hipMemsetAsync(deg, 0, 2 * (size_t)NN * 4 + 256, stream);   // deg + cnt (+pad)
    hipMemsetAsync(ssum, 0, 2 * 64 * 4 + 256, stream);          // ssum + ssq (+pad)

    // encode + BN + derived weights
    k_encode<<<NN / 32, 256, 0, stream>>>(x, fnw, fnb, h, ssum, ssq);
    k_params<<<1, 256, 0, stream>>>(ssum, ssq, gmm, beta, few, feb, aw, ab, fcb,
                                    bscale, bshift, uvec, c0vec);
    k_prep<<<dim3(192, LAYERS), 64, 0, stream>>>(fcw, aw, wt);
    k_bn<<<NN * 64 / 256, 256, 0, stream>>>(h, bscale, bshift);

    // CSR build
    k_hist<<<NE / 256, 256, 0, stream>>>(ei, deg);
    k_scan1<<<NB_SCAN, 256, 0, stream>>>(deg, row_ptr, totals);
    k_scan2<<<1, 64, 0, stream>>>(totals);
    k_scan3<<<(NN + 255) / 256, 256, 0, stream>>>(row_ptr, totals);
    k_scatter<<<NE / 256, 256, 0, stream>>>(ei, ea, row_ptr, cnt, csrc, cea);

    // 3 GAT layers
    for (int l = 0; l < LAYERS; l++) {
        k_tf<<<(NN + 63) / 64, 256, 0, stream>>>(h, wt + (size_t)l * 192 * 64,
                                                 fcb + l * 64, ai, packed);
        float* ho = (l == LAYERS - 1) ? out : h;
        k_edge<<<NN / 4, 256, 0, stream>>>(packed, ai, row_ptr, csrc, cea,
                                           uvec, c0vec, ho, l);
    }
    (void)in_sizes; (void)n_in; (void)out_size; (void)ws_size;
}

// Round 5
// 666.948 us; speedup vs baseline: 1.9744x; 1.4387x over previous
//
#include <hip/hip_runtime.h>
#include <math.h>

#define NN 100000
#define NE 1600000
#define LAYERS 3
#define NEG 0.2f
#define BN_EPS 1e-5f

#define SCAN_CHUNK 2048
#define NB_SCAN 49   // ceil(NN / SCAN_CHUNK)

typedef __attribute__((ext_vector_type(8))) short bf16x8;
typedef __attribute__((ext_vector_type(4))) float f32x4;

__device__ __forceinline__ unsigned f2bf(float x) {   // fp32 -> bf16 bits, RNE
    unsigned u = __float_as_uint(x);
    return (u + 0x7fffu + ((u >> 16) & 1u)) >> 16;
}

// ---------------- K1: node encode (x @ fc_node_w + b) + BN batch stats ----------------
__global__ __launch_bounds__(256) void k_encode(const float* __restrict__ x,
    const float* __restrict__ w, const float* __restrict__ b,
    float* __restrict__ h, float* __restrict__ stat_sum, float* __restrict__ stat_sq)
{
    int wave = threadIdx.x >> 6;
    int c    = threadIdx.x & 63;
    int n0   = blockIdx.x * 32 + wave * 8;
    float w0 = w[c], w1 = w[64 + c], w2 = w[128 + c], bc = b[c];
    float ps = 0.f, pq = 0.f;
    #pragma unroll
    for (int i = 0; i < 8; i++) {
        int n = n0 + i;
        float x0 = x[n * 3], x1 = x[n * 3 + 1], x2 = x[n * 3 + 2];
        float v = fmaf(x0, w0, fmaf(x1, w1, fmaf(x2, w2, bc)));
        h[n * 64 + c] = v;
        ps += v; pq += v * v;
    }
    __shared__ float rs[4][64], rq[4][64];
    rs[wave][c] = ps; rq[wave][c] = pq;
    __syncthreads();
    if (wave == 0) {
        float S = rs[0][c] + rs[1][c] + rs[2][c] + rs[3][c];
        float Q = rq[0][c] + rq[1][c] + rq[2][c] + rq[3][c];
        atomicAdd(&stat_sum[c], S);
        atomicAdd(&stat_sq[c], Q);
    }
}

// ---------------- K2: BN fold + per-layer edge constants u, c0, effective biases ----------------
// BN folded into layer 0: h_bn@M = h@(diag(sc)M) + sh@M. fcb_eff[0] = fcb[0] + sh@W0_0.
__global__ void k_params(const float* __restrict__ stat_sum, const float* __restrict__ stat_sq,
    const float* __restrict__ gamma, const float* __restrict__ beta,
    const float* __restrict__ few, const float* __restrict__ feb,
    const float* __restrict__ attn_w, const float* __restrict__ attn_b,
    const float* __restrict__ fcb, const float* __restrict__ fcw,
    float* __restrict__ bn_scale, float* __restrict__ u, float* __restrict__ c0,
    float* __restrict__ feff)
{
    __shared__ float ssh[64], sfe[3][64];
    int t = threadIdx.x;
    if (t < 64) {
        float mean = stat_sum[t] * (1.0f / NN);
        float var  = stat_sq[t] * (1.0f / NN) - mean * mean;
        float sc   = gamma[t] * rsqrtf(var + BN_EPS);
        bn_scale[t] = sc;
        ssh[t] = beta[t] - mean * sc;
    }
    __syncthreads();
    if (t < 64) {
        float v = 0.f;                              // v = sh @ W0_0
        for (int k = 0; k < 64; k++) v = fmaf(ssh[k], fcw[k * 64 + t], v);
        sfe[0][t] = fcb[t] + v;
        sfe[1][t] = fcb[64 + t];
        sfe[2][t] = fcb[128 + t];
    }
    __syncthreads();
    if (t < 192) {
        int l = t >> 6, c = t & 63;
        const float* AW = attn_w + l * 144 * 64;
        float uu = 0.f, cc = 0.f;
        for (int j = 0; j < 16; j++) {
            float wv = AW[(128 + j) * 64 + c];
            uu = fmaf(few[j], wv, uu);
            cc = fmaf(feb[j], wv, cc);
        }
        // bias of xi/xj paths: fcb_eff @ (Wi + Wj)
        float bi = 0.f;
        for (int tt = 0; tt < 64; tt++)
            bi = fmaf(sfe[l][tt], AW[tt * 64 + c] + AW[(64 + tt) * 64 + c], bi);
        u[t]    = uu;
        c0[t]   = cc + attn_b[t] + bi;
        feff[t] = sfe[l][c];
    }
}

// ---------------- K2b: transposed bf16 B-matrix [l][192 cols][64 k]: [W0 | W0@Wi | W0@Wj], layer0 row-scaled by sc ----------------
__global__ __launch_bounds__(64) void k_prep(const float* __restrict__ fcw,
    const float* __restrict__ aw, const float* __restrict__ bscale,
    unsigned short* __restrict__ wt)
{
    int g = blockIdx.x, l = blockIdx.y, k = threadIdx.x;
    const float* W0 = fcw + l * 4096;
    float scale = (l == 0) ? bscale[k] : 1.0f;
    float v;
    if (g < 64) {
        v = W0[k * 64 + g] * scale;
    } else {
        int c = g & 63;
        const float* Wx = aw + l * 144 * 64 + (g < 128 ? 0 : 4096);
        float s = 0.f;
        for (int tt = 0; tt < 64; tt++) s = fmaf(W0[k * 64 + tt], Wx[tt * 64 + c], s);
        v = s * scale;
    }
    wt[(l * 192 + g) * 64 + k] = (unsigned short)f2bf(v);
}

// ---------------- K4: degree histogram over dst ----------------
__global__ __launch_bounds__(256) void k_hist(const int* __restrict__ ei, int* __restrict__ deg)
{
    int k = blockIdx.x * 256 + threadIdx.x;   // grid exact NE/256
    atomicAdd(&deg[ei[NE + k]], 1);
}

// ---------------- K5-K7: exclusive scan -> row_ptr ----------------
__global__ __launch_bounds__(256) void k_scan1(const int* __restrict__ deg,
    int* __restrict__ row_ptr, int* __restrict__ totals)
{
    __shared__ int lds[256];
    int t = threadIdx.x;
    int base = blockIdx.x * SCAN_CHUNK + t * 8;
    int v[8]; int sum = 0;
    #pragma unroll
    for (int i = 0; i < 8; i++) {
        int idx = base + i;
        int xv = (idx < NN) ? deg[idx] : 0;
        sum += xv; v[i] = sum;
    }
    lds[t] = sum;
    __syncthreads();
    for (int off = 1; off < 256; off <<= 1) {
        int xv = (t >= off) ? lds[t - off] : 0;
        __syncthreads();
        lds[t] += xv;
        __syncthreads();
    }
    int excl = lds[t] - sum;
    #pragma unroll
    for (int i = 0; i < 8; i++) {
        int idx = base + i;
        if (idx < NN) row_ptr[idx + 1] = excl + v[i];
    }
    if (t == 255) totals[blockIdx.x] = lds[255];
}

__global__ void k_scan2(int* __restrict__ totals)
{
    __shared__ int lds[64];
    int t = threadIdx.x;
    int xv = (t < NB_SCAN) ? totals[t] : 0;
    lds[t] = xv;
    __syncthreads();
    for (int off = 1; off < 64; off <<= 1) {
        int y = (t >= off) ? lds[t - off] : 0;
        __syncthreads();
        lds[t] += y;
        __syncthreads();
    }
    if (t < NB_SCAN) totals[t] = lds[t] - xv;
}

__global__ __launch_bounds__(256) void k_scan3(int* __restrict__ row_ptr,
    const int* __restrict__ totals)
{
    int i = blockIdx.x * 256 + threadIdx.x;
    if (i == 0) row_ptr[0] = 0;
    if (i < NN) {
        int b = i >> 11;
        if (b > 0) row_ptr[i + 1] += totals[b];
    }
}

// ---------------- K8: scatter edges into CSR records {src, ea_bits} ----------------
__global__ __launch_bounds__(256) void k_scatter(const int* __restrict__ ei,
    const float* __restrict__ ea, const int* __restrict__ row_ptr,
    int* __restrict__ cnt, int2* __restrict__ er)
{
    int k = blockIdx.x * 256 + threadIdx.x;   // grid exact NE/256
    int d = ei[NE + k];
    int pos = atomicAdd(&cnt[d], 1);
    er[row_ptr[d] + pos] = make_int2(ei[k], __float_as_int(ea[k]));
}

// ---------------- K9: MFMA transform: [hl | ai | aj] = h @ [W0 | Mi | Mj]  (bf16 MFMA) ----------------
__global__ __launch_bounds__(256) void k_tf(const float* __restrict__ h,
    const unsigned short* __restrict__ wt_l, const float* __restrict__ feff_l,
    float* __restrict__ ai, unsigned* __restrict__ packed)
{
    int tid = threadIdx.x;
    int wv = tid >> 6, l = tid & 63;
    int r16 = l & 15, quad = l >> 4;
    int n0 = blockIdx.x * 64 + wv * 16;
    int na = n0 + r16; if (na >= NN) na = NN - 1;
    const float* hp = h + (size_t)na * 64 + quad * 8;
    bf16x8 a[2];
    #pragma unroll
    for (int ks = 0; ks < 2; ks++) {
        f32x4 lo = *(const f32x4*)(hp + ks * 32);
        f32x4 hi = *(const f32x4*)(hp + ks * 32 + 4);
        bf16x8 t;
        t[0] = (short)f2bf(lo[0]); t[1] = (short)f2bf(lo[1]);
        t[2] = (short)f2bf(lo[2]); t[3] = (short)f2bf(lo[3]);
        t[4] = (short)f2bf(hi[0]); t[5] = (short)f2bf(hi[1]);
        t[6] = (short)f2bf(hi[2]); t[7] = (short)f2bf(hi[3]);
        a[ks] = t;
    }
    f32x4 acc[12];
    #pragma unroll
    for (int i = 0; i < 12; i++) acc[i] = (f32x4){0.f, 0.f, 0.f, 0.f};
    const unsigned short* wb = wt_l + (size_t)r16 * 64 + quad * 8;
    #pragma unroll
    for (int cb = 0; cb < 12; cb++) {
        bf16x8 b0 = *(const bf16x8*)(wb + cb * 1024);
        bf16x8 b1 = *(const bf16x8*)(wb + cb * 1024 + 32);
        acc[cb] = __builtin_amdgcn_mfma_f32_16x16x32_bf16(a[0], b0, acc[cb], 0, 0, 0);
        acc[cb] = __builtin_amdgcn_mfma_f32_16x16x32_bf16(a[1], b1, acc[cb], 0, 0, 0);
    }
    #pragma unroll
    for (int r = 0; r < 4; r++) {
        int nd = n0 + quad * 4 + r;
        if (nd < NN) {
            size_t base = (size_t)nd * 64 + r16;
            #pragma unroll
            for (int cq = 0; cq < 4; cq++) {
                float hlv = acc[cq][r] + feff_l[cq * 16 + r16];
                float aiv = acc[4 + cq][r];
                float ajv = acc[8 + cq][r];
                ai[base + cq * 16]     = aiv;
                packed[base + cq * 16] = f2bf(hlv) | (f2bf(ajv) << 16);
            }
        }
    }
}

// ---------------- K10: fused softmax-attention aggregate, unroll-4 edge records ----------------
__global__ __launch_bounds__(256) void k_edge(const unsigned* __restrict__ packed,
    const float* __restrict__ ai, const int* __restrict__ row_ptr,
    const int2* __restrict__ er, const float* __restrict__ u, const float* __restrict__ c0,
    float* __restrict__ hout, int l)
{
    int w = threadIdx.x >> 6, c = threadIdx.x & 63;
    int n = blockIdx.x * 4 + w;                   // grid exact NN/4
    int beg = row_ptr[n], end = row_ptr[n + 1];
    float base = ai[n * 64 + c] + c0[l * 64 + c];
    float uc = u[l * 64 + c];
    const unsigned* __restrict__ pc = packed + c;
    float d0 = 0.f, d1 = 0.f, s0 = 0.f, s1 = 0.f;
    int k = beg;
    for (; k + 4 <= end; k += 4) {
        int2 e0 = er[k], e1 = er[k + 1], e2 = er[k + 2], e3 = er[k + 3];
        unsigned p0 = pc[(size_t)e0.x << 6];
        unsigned p1 = pc[(size_t)e1.x << 6];
        unsigned p2 = pc[(size_t)e2.x << 6];
        unsigned p3 = pc[(size_t)e3.x << 6];
        float a0 = fmaf(__int_as_float(e0.y), uc, base + __uint_as_float(p0 & 0xffff0000u));
        float a1 = fmaf(__int_as_float(e1.y), uc, base + __uint_as_float(p1 & 0xffff0000u));
        float a2 = fmaf(__int_as_float(e2.y), uc, base + __uint_as_float(p2 & 0xffff0000u));
        float a3 = fmaf(__int_as_float(e3.y), uc, base + __uint_as_float(p3 & 0xffff0000u));
        a0 = fmaxf(a0, NEG * a0); a1 = fmaxf(a1, NEG * a1);
        a2 = fmaxf(a2, NEG * a2); a3 = fmaxf(a3, NEG * a3);
        float x0 = __expf(a0), x1 = __expf(a1), x2 = __expf(a2), x3 = __expf(a3);
        d0 += x0; d1 += x1; d0 += x2; d1 += x3;
        s0 = fmaf(x0, __uint_as_float(p0 << 16), s0);
        s1 = fmaf(x1, __uint_as_float(p1 << 16), s1);
        s0 = fmaf(x2, __uint_as_float(p2 << 16), s0);
        s1 = fmaf(x3, __uint_as_float(p3 << 16), s1);
    }
    for (; k < end; k++) {
        int2 e0 = er[k];
        unsigned p0 = pc[(size_t)e0.x << 6];
        float a0 = fmaf(__int_as_float(e0.y), uc, base + __uint_as_float(p0 & 0xffff0000u));
        a0 = fmaxf(a0, NEG * a0);
        float x0 = __expf(a0);
        d0 += x0;
        s0 = fmaf(x0, __uint_as_float(p0 << 16), s0);
    }
    hout[n * 64 + c] = (s0 + s1) / (d0 + d1 + 1e-16f);
}

// ---------------- launch ----------------
extern "C" void kernel_launch(void* const* d_in, const int* in_sizes, int n_in,
                              void* d_out, int out_size, void* d_ws, size_t ws_size,
                              hipStream_t stream)
{
    const float* x    = (const float*)d_in[0];
    const float* ea   = (const float*)d_in[1];
    const int*   ei   = (const int*)d_in[2];
    const float* fnw  = (const float*)d_in[3];
    const float* fnb  = (const float*)d_in[4];
    const float* few  = (const float*)d_in[5];
    const float* feb  = (const float*)d_in[6];
    const float* gmm  = (const float*)d_in[7];
    const float* beta = (const float*)d_in[8];
    const float* fcw  = (const float*)d_in[9];
    const float* fcb  = (const float*)d_in[10];
    const float* aw   = (const float*)d_in[11];
    const float* ab   = (const float*)d_in[12];
    float* out = (float*)d_out;

    char* ws = (char*)d_ws;
    size_t off = 0;
    auto alloc = [&](size_t bytes) -> void* {
        void* p = ws + off;
        off += (bytes + 255) / 256 * 256;
        return p;
    };
    float*    h       = (float*)   alloc((size_t)NN * 64 * 4);
    float*    ai      = (float*)   alloc((size_t)NN * 64 * 4);
    unsigned* packed  = (unsigned*)alloc((size_t)NN * 64 * 4);
    int2*     er      = (int2*)    alloc((size_t)NE * 8);
    int*      row_ptr = (int*)     alloc((size_t)(NN + 1) * 4);
    int*      deg     = (int*)     alloc((size_t)NN * 4);   // deg + cnt contiguous: zero together
    int*      cnt     = (int*)     alloc((size_t)NN * 4);
    int*      totals  = (int*)     alloc(64 * 4);
    float*    ssum    = (float*)   alloc(64 * 4);           // ssum + ssq contiguous: zero together
    float*    ssq     = (float*)   alloc(64 * 4);
    float*    bscale  = (float*)   alloc(64 * 4);
    float*    uvec    = (float*)   alloc(192 * 4);
    float*    c0vec   = (float*)   alloc(192 * 4);
    float*    feff    = (float*)   alloc(192 * 4);
    unsigned short* wt = (unsigned short*)alloc((size_t)LAYERS * 192 * 64 * 2);

    hipMemsetAsync(deg, 0, 2 * (size_t)NN * 4 + 256, stream);   // deg + cnt (+pad)
    hipMemsetAsync(ssum, 0, 2 * 64 * 4, stream);                // ssum + ssq

    // encode + derived weights (BN folded into layer-0 weights)
    k_encode<<<NN / 32, 256, 0, stream>>>(x, fnw, fnb, h, ssum, ssq);
    k_params<<<1, 256, 0, stream>>>(ssum, ssq, gmm, beta, few, feb, aw, ab, fcb, fcw,
                                    bscale, uvec, c0vec, feff);
    k_prep<<<dim3(192, LAYERS), 64, 0, stream>>>(fcw, aw, bscale, wt);

    // CSR build
    k_hist<<<NE / 256, 256, 0, stream>>>(ei, deg);
    k_scan1<<<NB_SCAN, 256, 0, stream>>>(deg, row_ptr, totals);
    k_scan2<<<1, 64, 0, stream>>>(totals);
    k_scan3<<<(NN + 255) / 256, 256, 0, stream>>>(row_ptr, totals);
    k_scatter<<<NE / 256, 256, 0, stream>>>(ei, ea, row_ptr, cnt, er);

    // 3 GAT layers
    for (int l = 0; l < LAYERS; l++) {
        k_tf<<<(NN + 63) / 64, 256, 0, stream>>>(h, wt + (size_t)l * 192 * 64,
                                                 feff + l * 64, ai, packed);
        float* ho = (l == LAYERS - 1) ? out : h;
        k_edge<<<NN / 4, 256, 0, stream>>>(packed, ai, row_ptr, er,
                                           uvec, c0vec, ho, l);
    }
    (void)in_sizes; (void)n_in; (void)out_size; (void)ws_size;
}

// Round 6
// 575.836 us; speedup vs baseline: 2.2867x; 1.1582x over previous
//
#include <hip/hip_runtime.h>
#include <math.h>

#define NN 100000
#define NE 1600000
#define LAYERS 3
#define NEG 0.2f
#define BN_EPS 1e-5f

#define NB 196            // buckets = ceil(NN / 512)
#define NWG 128           // multisplit workgroups
#define CHUNK 12500       // NE / NWG exactly

typedef __attribute__((ext_vector_type(8))) short bf16x8;
typedef __attribute__((ext_vector_type(4))) float f32x4;

__device__ __forceinline__ unsigned f2bf(float x) {   // fp32 -> bf16 bits, RNE
    unsigned u = __float_as_uint(x);
    return (u + 0x7fffu + ((u >> 16) & 1u)) >> 16;
}

// ---------------- K1: node encode (x @ fc_node_w + b) + BN batch stats ----------------
__global__ __launch_bounds__(256) void k_encode(const float* __restrict__ x,
    const float* __restrict__ w, const float* __restrict__ b,
    float* __restrict__ h, float* __restrict__ stat_sum, float* __restrict__ stat_sq)
{
    int wave = threadIdx.x >> 6;
    int c    = threadIdx.x & 63;
    int n0   = blockIdx.x * 32 + wave * 8;
    float w0 = w[c], w1 = w[64 + c], w2 = w[128 + c], bc = b[c];
    float ps = 0.f, pq = 0.f;
    #pragma unroll
    for (int i = 0; i < 8; i++) {
        int n = n0 + i;
        float x0 = x[n * 3], x1 = x[n * 3 + 1], x2 = x[n * 3 + 2];
        float v = fmaf(x0, w0, fmaf(x1, w1, fmaf(x2, w2, bc)));
        h[n * 64 + c] = v;
        ps += v; pq += v * v;
    }
    __shared__ float rs[4][64], rq[4][64];
    rs[wave][c] = ps; rq[wave][c] = pq;
    __syncthreads();
    if (wave == 0) {
        float S = rs[0][c] + rs[1][c] + rs[2][c] + rs[3][c];
        float Q = rq[0][c] + rq[1][c] + rq[2][c] + rq[3][c];
        atomicAdd(&stat_sum[c], S);
        atomicAdd(&stat_sq[c], Q);
    }
}

// ---------------- K2: BN fold + per-layer edge constants u, c0, effective biases ----------------
__global__ void k_params(const float* __restrict__ stat_sum, const float* __restrict__ stat_sq,
    const float* __restrict__ gamma, const float* __restrict__ beta,
    const float* __restrict__ few, const float* __restrict__ feb,
    const float* __restrict__ attn_w, const float* __restrict__ attn_b,
    const float* __restrict__ fcb, const float* __restrict__ fcw,
    float* __restrict__ bn_scale, float* __restrict__ u, float* __restrict__ c0,
    float* __restrict__ feff)
{
    __shared__ float ssh[64], sfe[3][64];
    int t = threadIdx.x;
    if (t < 64) {
        float mean = stat_sum[t] * (1.0f / NN);
        float var  = stat_sq[t] * (1.0f / NN) - mean * mean;
        float sc   = gamma[t] * rsqrtf(var + BN_EPS);
        bn_scale[t] = sc;
        ssh[t] = beta[t] - mean * sc;
    }
    __syncthreads();
    if (t < 64) {
        float v = 0.f;                              // v = sh @ W0_0
        for (int k = 0; k < 64; k++) v = fmaf(ssh[k], fcw[k * 64 + t], v);
        sfe[0][t] = fcb[t] + v;
        sfe[1][t] = fcb[64 + t];
        sfe[2][t] = fcb[128 + t];
    }
    __syncthreads();
    if (t < 192) {
        int l = t >> 6, c = t & 63;
        const float* AW = attn_w + l * 144 * 64;
        float uu = 0.f, cc = 0.f;
        for (int j = 0; j < 16; j++) {
            float wv = AW[(128 + j) * 64 + c];
            uu = fmaf(few[j], wv, uu);
            cc = fmaf(feb[j], wv, cc);
        }
        float bi = 0.f;                             // fcb_eff @ (Wi + Wj)
        for (int tt = 0; tt < 64; tt++)
            bi = fmaf(sfe[l][tt], AW[tt * 64 + c] + AW[(64 + tt) * 64 + c], bi);
        u[t]    = uu;
        c0[t]   = cc + attn_b[t] + bi;
        feff[t] = sfe[l][c];
    }
}

// ---------------- K2b: transposed bf16 B-matrix [l][192 cols][64 k], layer0 row-scaled ----------------
__global__ __launch_bounds__(64) void k_prep(const float* __restrict__ fcw,
    const float* __restrict__ aw, const float* __restrict__ bscale,
    unsigned short* __restrict__ wt)
{
    int g = blockIdx.x, l = blockIdx.y, k = threadIdx.x;
    const float* W0 = fcw + l * 4096;
    float scale = (l == 0) ? bscale[k] : 1.0f;
    float v;
    if (g < 64) {
        v = W0[k * 64 + g] * scale;
    } else {
        int c = g & 63;
        const float* Wx = aw + l * 144 * 64 + (g < 128 ? 0 : 4096);
        float s = 0.f;
        for (int tt = 0; tt < 64; tt++) s = fmaf(W0[k * 64 + tt], Wx[tt * 64 + c], s);
        v = s * scale;
    }
    wt[(l * 192 + g) * 64 + k] = (unsigned short)f2bf(v);
}

// ---------------- CSR build: deterministic two-level multisplit ----------------
// A: per-WG bucket histogram
__global__ __launch_bounds__(256) void k_bcount(const int* __restrict__ ei,
    int* __restrict__ counts)
{
    __shared__ int hist[NB];
    int t = threadIdx.x, wg = blockIdx.x;
    if (t < NB) hist[t] = 0;
    __syncthreads();
    int base = wg * CHUNK;
    for (int i = t; i < CHUNK; i += 256)
        atomicAdd(&hist[ei[NE + base + i] >> 9], 1);
    __syncthreads();
    if (t < NB) counts[t * NWG + wg] = hist[t];
}

// scan: counts -> global exclusive offsets; bucket bases; row_ptr[NN]
__global__ __launch_bounds__(256) void k_bscan(int* __restrict__ counts,
    int* __restrict__ bbase, int* __restrict__ row_ptr)
{
    __shared__ int s_tot[256];
    int t = threadIdx.x;
    int tot = 0;
    if (t < NB)
        for (int w = 0; w < NWG; w++) tot += counts[t * NWG + w];
    s_tot[t] = tot;
    __syncthreads();
    for (int off = 1; off < 256; off <<= 1) {
        int v = (t >= off) ? s_tot[t - off] : 0;
        __syncthreads();
        s_tot[t] += v;
        __syncthreads();
    }
    int excl = s_tot[t] - tot;
    if (t < NB) {
        bbase[t] = excl;
        int run = excl;
        for (int w = 0; w < NWG; w++) {
            int c = counts[t * NWG + w];
            counts[t * NWG + w] = run;
            run += c;
        }
        if (t == NB - 1) {
            bbase[NB] = run;          // == NE
            row_ptr[NN] = run;
        }
    }
}

// B: placement into bucket-grouped records {(dl<<17)|src, ea_bits}
__global__ __launch_bounds__(256) void k_bwrite(const int* __restrict__ ei,
    const float* __restrict__ ea, const int* __restrict__ counts,
    int2* __restrict__ brec)
{
    __shared__ int off[NB];
    int t = threadIdx.x, wg = blockIdx.x;
    if (t < NB) off[t] = counts[t * NWG + wg];
    __syncthreads();
    int base = wg * CHUNK;
    for (int i = t; i < CHUNK; i += 256) {
        int k = base + i;
        int s = ei[k], d = ei[NE + k];
        int b = d >> 9;
        int j = atomicAdd(&off[b], 1);
        brec[j] = make_int2(((d & 511) << 17) | s, __float_as_int(ea[k]));
    }
}

// C: per-bucket CSR finalize: row_ptr + dst-sorted er (one WG per bucket)
__global__ __launch_bounds__(256) void k_csr(const int2* __restrict__ brec,
    const int* __restrict__ bbase, int* __restrict__ row_ptr, int2* __restrict__ er)
{
    __shared__ int s_cnt[512], s_excl[512], s_ts[256];
    int t = threadIdx.x, b = blockIdx.x;
    int beg = bbase[b], end = bbase[b + 1];
    s_cnt[t] = 0; s_cnt[t + 256] = 0;
    __syncthreads();
    for (int i = beg + t; i < end; i += 256)
        atomicAdd(&s_cnt[brec[i].x >> 17], 1);
    __syncthreads();
    int a0 = s_cnt[2 * t], a1 = s_cnt[2 * t + 1];
    int ts = a0 + a1;
    s_ts[t] = ts;
    __syncthreads();
    for (int off = 1; off < 256; off <<= 1) {
        int v = (t >= off) ? s_ts[t - off] : 0;
        __syncthreads();
        s_ts[t] += v;
        __syncthreads();
    }
    int et = s_ts[t] - ts;
    s_excl[2 * t] = et; s_excl[2 * t + 1] = et + a0;
    // reset counters for placement
    s_cnt[t] = 0; s_cnt[t + 256] = 0;
    __syncthreads();
    // row_ptr
    #pragma unroll
    for (int q = 0; q < 2; q++) {
        int dl = t + q * 256;
        int n = b * 512 + dl;
        if (n < NN) row_ptr[n] = beg + s_excl[dl];
    }
    // place
    for (int i = beg + t; i < end; i += 256) {
        int2 r = brec[i];
        int dl = r.x >> 17;
        int pos = atomicAdd(&s_cnt[dl], 1);
        er[beg + s_excl[dl] + pos] = make_int2(r.x & 0x1FFFF, r.y);
    }
}

// ---------------- K9: MFMA transform: [hl | ai | aj] = h @ [W0 | Mi | Mj] ----------------
__global__ __launch_bounds__(256) void k_tf(const float* __restrict__ h,
    const unsigned short* __restrict__ wt_l, const float* __restrict__ feff_l,
    float* __restrict__ ai, unsigned* __restrict__ packed)
{
    int tid = threadIdx.x;
    int wv = tid >> 6, l = tid & 63;
    int r16 = l & 15, quad = l >> 4;
    int n0 = blockIdx.x * 64 + wv * 16;
    int na = n0 + r16; if (na >= NN) na = NN - 1;
    const float* hp = h + (size_t)na * 64 + quad * 8;
    bf16x8 a[2];
    #pragma unroll
    for (int ks = 0; ks < 2; ks++) {
        f32x4 lo = *(const f32x4*)(hp + ks * 32);
        f32x4 hi = *(const f32x4*)(hp + ks * 32 + 4);
        bf16x8 t;
        t[0] = (short)f2bf(lo[0]); t[1] = (short)f2bf(lo[1]);
        t[2] = (short)f2bf(lo[2]); t[3] = (short)f2bf(lo[3]);
        t[4] = (short)f2bf(hi[0]); t[5] = (short)f2bf(hi[1]);
        t[6] = (short)f2bf(hi[2]); t[7] = (short)f2bf(hi[3]);
        a[ks] = t;
    }
    f32x4 acc[12];
    #pragma unroll
    for (int i = 0; i < 12; i++) acc[i] = (f32x4){0.f, 0.f, 0.f, 0.f};
    const unsigned short* wb = wt_l + (size_t)r16 * 64 + quad * 8;
    #pragma unroll
    for (int cb = 0; cb < 12; cb++) {
        bf16x8 b0 = *(const bf16x8*)(wb + cb * 1024);
        bf16x8 b1 = *(const bf16x8*)(wb + cb * 1024 + 32);
        acc[cb] = __builtin_amdgcn_mfma_f32_16x16x32_bf16(a[0], b0, acc[cb], 0, 0, 0);
        acc[cb] = __builtin_amdgcn_mfma_f32_16x16x32_bf16(a[1], b1, acc[cb], 0, 0, 0);
    }
    #pragma unroll
    for (int r = 0; r < 4; r++) {
        int nd = n0 + quad * 4 + r;
        if (nd < NN) {
            size_t base = (size_t)nd * 64 + r16;
            #pragma unroll
            for (int cq = 0; cq < 4; cq++) {
                float hlv = acc[cq][r] + feff_l[cq * 16 + r16];
                float aiv = acc[4 + cq][r];
                float ajv = acc[8 + cq][r];
                ai[base + cq * 16]     = aiv;
                packed[base + cq * 16] = f2bf(hlv) | (f2bf(ajv) << 16);
            }
        }
    }
}

// ---------------- K10: fused softmax-attention aggregate, unroll-4 ----------------
__global__ __launch_bounds__(256) void k_edge(const unsigned* __restrict__ packed,
    const float* __restrict__ ai, const int* __restrict__ row_ptr,
    const int2* __restrict__ er, const float* __restrict__ u, const float* __restrict__ c0,
    float* __restrict__ hout, int l)
{
    int w = threadIdx.x >> 6, c = threadIdx.x & 63;
    int n = blockIdx.x * 4 + w;                   // grid exact NN/4
    int beg = row_ptr[n], end = row_ptr[n + 1];
    float base = ai[n * 64 + c] + c0[l * 64 + c];
    float uc = u[l * 64 + c];
    const unsigned* __restrict__ pc = packed + c;
    float d0 = 0.f, d1 = 0.f, s0 = 0.f, s1 = 0.f;
    int k = beg;
    for (; k + 4 <= end; k += 4) {
        int2 e0 = er[k], e1 = er[k + 1], e2 = er[k + 2], e3 = er[k + 3];
        unsigned p0 = pc[(size_t)e0.x << 6];
        unsigned p1 = pc[(size_t)e1.x << 6];
        unsigned p2 = pc[(size_t)e2.x << 6];
        unsigned p3 = pc[(size_t)e3.x << 6];
        float a0 = fmaf(__int_as_float(e0.y), uc, base + __uint_as_float(p0 & 0xffff0000u));
        float a1 = fmaf(__int_as_float(e1.y), uc, base + __uint_as_float(p1 & 0xffff0000u));
        float a2 = fmaf(__int_as_float(e2.y), uc, base + __uint_as_float(p2 & 0xffff0000u));
        float a3 = fmaf(__int_as_float(e3.y), uc, base + __uint_as_float(p3 & 0xffff0000u));
        a0 = fmaxf(a0, NEG * a0); a1 = fmaxf(a1, NEG * a1);
        a2 = fmaxf(a2, NEG * a2); a3 = fmaxf(a3, NEG * a3);
        float x0 = __expf(a0), x1 = __expf(a1), x2 = __expf(a2), x3 = __expf(a3);
        d0 += x0; d1 += x1; d0 += x2; d1 += x3;
        s0 = fmaf(x0, __uint_as_float(p0 << 16), s0);
        s1 = fmaf(x1, __uint_as_float(p1 << 16), s1);
        s0 = fmaf(x2, __uint_as_float(p2 << 16), s0);
        s1 = fmaf(x3, __uint_as_float(p3 << 16), s1);
    }
    for (; k < end; k++) {
        int2 e0 = er[k];
        unsigned p0 = pc[(size_t)e0.x << 6];
        float a0 = fmaf(__int_as_float(e0.y), uc, base + __uint_as_float(p0 & 0xffff0000u));
        a0 = fmaxf(a0, NEG * a0);
        float x0 = __expf(a0);
        d0 += x0;
        s0 = fmaf(x0, __uint_as_float(p0 << 16), s0);
    }
    hout[n * 64 + c] = (s0 + s1) / (d0 + d1 + 1e-16f);
}

// ---------------- launch ----------------
extern "C" void kernel_launch(void* const* d_in, const int* in_sizes, int n_in,
                              void* d_out, int out_size, void* d_ws, size_t ws_size,
                              hipStream_t stream)
{
    const float* x    = (const float*)d_in[0];
    const float* ea   = (const float*)d_in[1];
    const int*   ei   = (const int*)d_in[2];
    const float* fnw  = (const float*)d_in[3];
    const float* fnb  = (const float*)d_in[4];
    const float* few  = (const float*)d_in[5];
    const float* feb  = (const float*)d_in[6];
    const float* gmm  = (const float*)d_in[7];
    const float* beta = (const float*)d_in[8];
    const float* fcw  = (const float*)d_in[9];
    const float* fcb  = (const float*)d_in[10];
    const float* aw   = (const float*)d_in[11];
    const float* ab   = (const float*)d_in[12];
    float* out = (float*)d_out;

    char* ws = (char*)d_ws;
    size_t off = 0;
    auto alloc = [&](size_t bytes) -> void* {
        void* p = ws + off;
        off += (bytes + 255) / 256 * 256;
        return p;
    };
    float*    h       = (float*)   alloc((size_t)NN * 64 * 4);
    float*    ai      = (float*)   alloc((size_t)NN * 64 * 4);
    unsigned* packed  = (unsigned*)alloc((size_t)NN * 64 * 4);
    int2*     er      = (int2*)    alloc((size_t)NE * 8);
    int2*     brec    = (int2*)    alloc((size_t)NE * 8);
    int*      row_ptr = (int*)     alloc((size_t)(NN + 1) * 4);
    int*      counts  = (int*)     alloc((size_t)NB * NWG * 4);
    int*      bbase   = (int*)     alloc((NB + 1) * 4);
    float*    ssum    = (float*)   alloc(64 * 4);           // ssum + ssq contiguous: zero together
    float*    ssq     = (float*)   alloc(64 * 4);
    float*    bscale  = (float*)   alloc(64 * 4);
    float*    uvec    = (float*)   alloc(192 * 4);
    float*    c0vec   = (float*)   alloc(192 * 4);
    float*    feff    = (float*)   alloc(192 * 4);
    unsigned short* wt = (unsigned short*)alloc((size_t)LAYERS * 192 * 64 * 2);

    hipMemsetAsync(ssum, 0, 2 * 64 * 4, stream);            // ssum + ssq

    // encode + derived weights (BN folded into layer-0 weights)
    k_encode<<<NN / 32, 256, 0, stream>>>(x, fnw, fnb, h, ssum, ssq);
    k_params<<<1, 256, 0, stream>>>(ssum, ssq, gmm, beta, few, feb, aw, ab, fcb, fcw,
                                    bscale, uvec, c0vec, feff);
    k_prep<<<dim3(192, LAYERS), 64, 0, stream>>>(fcw, aw, bscale, wt);

    // CSR build via multisplit
    k_bcount<<<NWG, 256, 0, stream>>>(ei, counts);
    k_bscan<<<1, 256, 0, stream>>>(counts, bbase, row_ptr);
    k_bwrite<<<NWG, 256, 0, stream>>>(ei, ea, counts, brec);
    k_csr<<<NB, 256, 0, stream>>>(brec, bbase, row_ptr, er);

    // 3 GAT layers
    for (int l = 0; l < LAYERS; l++) {
        k_tf<<<(NN + 63) / 64, 256, 0, stream>>>(h, wt + (size_t)l * 192 * 64,
                                                 feff + l * 64, ai, packed);
        float* ho = (l == LAYERS - 1) ? out : h;
        k_edge<<<NN / 4, 256, 0, stream>>>(packed, ai, row_ptr, er,
                                           uvec, c0vec, ho, l);
    }
    (void)in_sizes; (void)n_in; (void)out_size; (void)ws_size;
}

// Round 7
// 489.820 us; speedup vs baseline: 2.6883x; 1.1756x over previous
//
#include <hip/hip_runtime.h>
#include <math.h>

#define NN 100000
#define NE 1600000
#define LAYERS 3
#define NEG 0.2f
#define BN_EPS 1e-5f

#define NB 196            // buckets = ceil(NN / 512)
#define NWG 128           // multisplit workgroups
#define CHUNK 12500       // NE / NWG exactly
#define MOMB 304          // k_moments blocks

typedef __attribute__((ext_vector_type(8))) short bf16x8;
typedef __attribute__((ext_vector_type(4))) float f32x4;

__device__ __forceinline__ unsigned f2bf(float x) {   // fp32 -> bf16 bits, RNE
    unsigned u = __float_as_uint(x);
    return (u + 0x7fffu + ((u >> 16) & 1u)) >> 16;
}

// ---------------- K1: x moments (Sx[3], Sxx^T[6]) -> analytic BN stats ----------------
__global__ __launch_bounds__(256) void k_moments(const float* __restrict__ x,
    float* __restrict__ mom)
{
    float s0=0,s1=0,s2=0,m00=0,m01=0,m02=0,m11=0,m12=0,m22=0;
    for (int n = blockIdx.x * 256 + threadIdx.x; n < NN; n += MOMB * 256) {
        float a = x[n*3], b = x[n*3+1], c = x[n*3+2];
        s0 += a; s1 += b; s2 += c;
        m00 = fmaf(a,a,m00); m01 = fmaf(a,b,m01); m02 = fmaf(a,c,m02);
        m11 = fmaf(b,b,m11); m12 = fmaf(b,c,m12); m22 = fmaf(c,c,m22);
    }
    #pragma unroll
    for (int off = 32; off; off >>= 1) {
        s0 += __shfl_xor(s0, off); s1 += __shfl_xor(s1, off); s2 += __shfl_xor(s2, off);
        m00 += __shfl_xor(m00, off); m01 += __shfl_xor(m01, off); m02 += __shfl_xor(m02, off);
        m11 += __shfl_xor(m11, off); m12 += __shfl_xor(m12, off); m22 += __shfl_xor(m22, off);
    }
    __shared__ float red[4][9];
    int wave = threadIdx.x >> 6, lane = threadIdx.x & 63;
    if (lane == 0) {
        red[wave][0]=s0; red[wave][1]=s1; red[wave][2]=s2;
        red[wave][3]=m00; red[wave][4]=m01; red[wave][5]=m02;
        red[wave][6]=m11; red[wave][7]=m12; red[wave][8]=m22;
    }
    __syncthreads();
    if (threadIdx.x < 9) {
        float v = red[0][threadIdx.x] + red[1][threadIdx.x] + red[2][threadIdx.x] + red[3][threadIdx.x];
        atomicAdd(&mom[threadIdx.x], v);
    }
}

// ---------------- K2: analytic BN fold + per-layer edge constants u, c0, effective biases ----------------
__global__ void k_params(const float* __restrict__ mom,
    const float* __restrict__ fnw, const float* __restrict__ fnb,
    const float* __restrict__ gamma, const float* __restrict__ beta,
    const float* __restrict__ few, const float* __restrict__ feb,
    const float* __restrict__ attn_w, const float* __restrict__ attn_b,
    const float* __restrict__ fcb, const float* __restrict__ fcw,
    float* __restrict__ bn_scale, float* __restrict__ u, float* __restrict__ c0,
    float* __restrict__ feff)
{
    __shared__ float ssh[64], sfe[3][64];
    int t = threadIdx.x;
    if (t < 64) {
        float w0 = fnw[t], w1 = fnw[64 + t], w2 = fnw[128 + t], bc = fnb[t];
        float dot  = mom[0]*w0 + mom[1]*w1 + mom[2]*w2;                     // s . w_c
        float quad = mom[3]*w0*w0 + 2.f*mom[4]*w0*w1 + 2.f*mom[5]*w0*w2
                   + mom[6]*w1*w1 + 2.f*mom[7]*w1*w2 + mom[8]*w2*w2;       // w^T M w
        float mean = dot * (1.0f / NN) + bc;
        float eh2  = quad * (1.0f / NN) + 2.f * bc * dot * (1.0f / NN) + bc * bc;
        float var  = eh2 - mean * mean;
        float sc   = gamma[t] * rsqrtf(var + BN_EPS);
        bn_scale[t] = sc;
        ssh[t] = beta[t] - mean * sc;
    }
    __syncthreads();
    if (t < 64) {
        float v = 0.f;                              // v = sh @ W0_0
        for (int k = 0; k < 64; k++) v = fmaf(ssh[k], fcw[k * 64 + t], v);
        sfe[0][t] = fcb[t] + v;
        sfe[1][t] = fcb[64 + t];
        sfe[2][t] = fcb[128 + t];
    }
    __syncthreads();
    if (t < 192) {
        int l = t >> 6, c = t & 63;
        const float* AW = attn_w + l * 144 * 64;
        float uu = 0.f, cc = 0.f;
        for (int j = 0; j < 16; j++) {
            float wv = AW[(128 + j) * 64 + c];
            uu = fmaf(few[j], wv, uu);
            cc = fmaf(feb[j], wv, cc);
        }
        float bi = 0.f;                             // fcb_eff @ (Wi + Wj)
        for (int tt = 0; tt < 64; tt++)
            bi = fmaf(sfe[l][tt], AW[tt * 64 + c] + AW[(64 + tt) * 64 + c], bi);
        u[t]    = uu;
        c0[t]   = cc + attn_b[t] + bi;
        feff[t] = sfe[l][c];
    }
}

// ---------------- K2b: transposed bf16 B-matrix [l][192 cols][64 k], layer0 row-scaled ----------------
__global__ __launch_bounds__(64) void k_prep(const float* __restrict__ fcw,
    const float* __restrict__ aw, const float* __restrict__ bscale,
    unsigned short* __restrict__ wt)
{
    int g = blockIdx.x, l = blockIdx.y, k = threadIdx.x;
    const float* W0 = fcw + l * 4096;
    float scale = (l == 0) ? bscale[k] : 1.0f;
    float v;
    if (g < 64) {
        v = W0[k * 64 + g] * scale;
    } else {
        int c = g & 63;
        const float* Wx = aw + l * 144 * 64 + (g < 128 ? 0 : 4096);
        float s = 0.f;
        for (int tt = 0; tt < 64; tt++) s = fmaf(W0[k * 64 + tt], Wx[tt * 64 + c], s);
        v = s * scale;
    }
    wt[(l * 192 + g) * 64 + k] = (unsigned short)f2bf(v);
}

// ---------------- CSR build: deterministic two-level multisplit ----------------
__global__ __launch_bounds__(256) void k_bcount(const int* __restrict__ ei,
    int* __restrict__ counts)
{
    __shared__ int hist[NB];
    int t = threadIdx.x, wg = blockIdx.x;
    if (t < NB) hist[t] = 0;
    __syncthreads();
    int base = wg * CHUNK;
    for (int i = t; i < CHUNK; i += 256)
        atomicAdd(&hist[ei[NE + base + i] >> 9], 1);
    __syncthreads();
    if (t < NB) counts[t * NWG + wg] = hist[t];
}

__global__ __launch_bounds__(256) void k_bscan(int* __restrict__ counts,
    int* __restrict__ bbase, int* __restrict__ row_ptr)
{
    __shared__ int s_tot[256];
    int t = threadIdx.x;
    int tot = 0;
    if (t < NB)
        for (int w = 0; w < NWG; w++) tot += counts[t * NWG + w];
    s_tot[t] = tot;
    __syncthreads();
    for (int off = 1; off < 256; off <<= 1) {
        int v = (t >= off) ? s_tot[t - off] : 0;
        __syncthreads();
        s_tot[t] += v;
        __syncthreads();
    }
    int excl = s_tot[t] - tot;
    if (t < NB) {
        bbase[t] = excl;
        int run = excl;
        for (int w = 0; w < NWG; w++) {
            int c = counts[t * NWG + w];
            counts[t * NWG + w] = run;
            run += c;
        }
        if (t == NB - 1) {
            bbase[NB] = run;          // == NE
            row_ptr[NN] = run;
        }
    }
}

__global__ __launch_bounds__(256) void k_bwrite(const int* __restrict__ ei,
    const float* __restrict__ ea, const int* __restrict__ counts,
    int2* __restrict__ brec)
{
    __shared__ int off[NB];
    int t = threadIdx.x, wg = blockIdx.x;
    if (t < NB) off[t] = counts[t * NWG + wg];
    __syncthreads();
    int base = wg * CHUNK;
    for (int i = t; i < CHUNK; i += 256) {
        int k = base + i;
        int s = ei[k], d = ei[NE + k];
        int b = d >> 9;
        int j = atomicAdd(&off[b], 1);
        brec[j] = make_int2(((d & 511) << 17) | s, __float_as_int(ea[k]));
    }
}

__global__ __launch_bounds__(256) void k_csr(const int2* __restrict__ brec,
    const int* __restrict__ bbase, int* __restrict__ row_ptr, int2* __restrict__ er)
{
    __shared__ int s_cnt[512], s_excl[512], s_ts[256];
    int t = threadIdx.x, b = blockIdx.x;
    int beg = bbase[b], end = bbase[b + 1];
    s_cnt[t] = 0; s_cnt[t + 256] = 0;
    __syncthreads();
    for (int i = beg + t; i < end; i += 256)
        atomicAdd(&s_cnt[brec[i].x >> 17], 1);
    __syncthreads();
    int a0 = s_cnt[2 * t], a1 = s_cnt[2 * t + 1];
    int ts = a0 + a1;
    s_ts[t] = ts;
    __syncthreads();
    for (int off = 1; off < 256; off <<= 1) {
        int v = (t >= off) ? s_ts[t - off] : 0;
        __syncthreads();
        s_ts[t] += v;
        __syncthreads();
    }
    int et = s_ts[t] - ts;
    s_excl[2 * t] = et; s_excl[2 * t + 1] = et + a0;
    s_cnt[t] = 0; s_cnt[t + 256] = 0;
    __syncthreads();
    #pragma unroll
    for (int q = 0; q < 2; q++) {
        int dl = t + q * 256;
        int n = b * 512 + dl;
        if (n < NN) row_ptr[n] = beg + s_excl[dl];
    }
    for (int i = beg + t; i < end; i += 256) {
        int2 r = brec[i];
        int dl = r.x >> 17;
        int pos = atomicAdd(&s_cnt[dl], 1);
        er[beg + s_excl[dl] + pos] = make_int2(r.x & 0x1FFFF, r.y);
    }
}

// ---------------- K9: MFMA transform: [hl | ai | aj] = A @ [W0 | Mi | Mj] ----------------
// FIRST: A-fragments computed on the fly from x (pre-BN h = x@fnw+fnb)
template<bool FIRST>
__global__ __launch_bounds__(256) void k_tf(const float* __restrict__ h,
    const float* __restrict__ xin, const float* __restrict__ fnw, const float* __restrict__ fnb,
    const unsigned short* __restrict__ wt_l, const float* __restrict__ feff_l,
    float* __restrict__ ai, unsigned* __restrict__ packed)
{
    int tid = threadIdx.x;
    int wv = tid >> 6, l = tid & 63;
    int r16 = l & 15, quad = l >> 4;
    int n0 = blockIdx.x * 64 + wv * 16;
    int na = n0 + r16; if (na >= NN) na = NN - 1;
    bf16x8 a[2];
    if (FIRST) {
        float x0 = xin[na*3], x1 = xin[na*3+1], x2 = xin[na*3+2];
        #pragma unroll
        for (int ks = 0; ks < 2; ks++) {
            bf16x8 t;
            #pragma unroll
            for (int e = 0; e < 8; e++) {
                int c = quad * 8 + ks * 32 + e;
                float v = fmaf(x0, fnw[c], fmaf(x1, fnw[64 + c], fmaf(x2, fnw[128 + c], fnb[c])));
                t[e] = (short)f2bf(v);
            }
            a[ks] = t;
        }
    } else {
        const float* hp = h + (size_t)na * 64 + quad * 8;
        #pragma unroll
        for (int ks = 0; ks < 2; ks++) {
            f32x4 lo = *(const f32x4*)(hp + ks * 32);
            f32x4 hi = *(const f32x4*)(hp + ks * 32 + 4);
            bf16x8 t;
            t[0] = (short)f2bf(lo[0]); t[1] = (short)f2bf(lo[1]);
            t[2] = (short)f2bf(lo[2]); t[3] = (short)f2bf(lo[3]);
            t[4] = (short)f2bf(hi[0]); t[5] = (short)f2bf(hi[1]);
            t[6] = (short)f2bf(hi[2]); t[7] = (short)f2bf(hi[3]);
            a[ks] = t;
        }
    }
    f32x4 acc[12];
    #pragma unroll
    for (int i = 0; i < 12; i++) acc[i] = (f32x4){0.f, 0.f, 0.f, 0.f};
    const unsigned short* wb = wt_l + (size_t)r16 * 64 + quad * 8;
    #pragma unroll
    for (int cb = 0; cb < 12; cb++) {
        bf16x8 b0 = *(const bf16x8*)(wb + cb * 1024);
        bf16x8 b1 = *(const bf16x8*)(wb + cb * 1024 + 32);
        acc[cb] = __builtin_amdgcn_mfma_f32_16x16x32_bf16(a[0], b0, acc[cb], 0, 0, 0);
        acc[cb] = __builtin_amdgcn_mfma_f32_16x16x32_bf16(a[1], b1, acc[cb], 0, 0, 0);
    }
    #pragma unroll
    for (int r = 0; r < 4; r++) {
        int nd = n0 + quad * 4 + r;
        if (nd < NN) {
            size_t base = (size_t)nd * 64 + r16;
            #pragma unroll
            for (int cq = 0; cq < 4; cq++) {
                float hlv = acc[cq][r] + feff_l[cq * 16 + r16];
                float aiv = acc[4 + cq][r];
                float ajv = acc[8 + cq][r];
                ai[base + cq * 16]     = aiv;
                packed[base + cq * 16] = f2bf(hlv) | (f2bf(ajv) << 16);
            }
        }
    }
}

// ---------------- K10: fused softmax-attention aggregate, unroll-8 ----------------
__global__ __launch_bounds__(256) void k_edge(const unsigned* __restrict__ packed,
    const float* __restrict__ ai, const int* __restrict__ row_ptr,
    const int2* __restrict__ er, const float* __restrict__ u, const float* __restrict__ c0,
    float* __restrict__ hout, int l)
{
    int w = threadIdx.x >> 6, c = threadIdx.x & 63;
    int n = blockIdx.x * 4 + w;                   // grid exact NN/4
    int beg = row_ptr[n], end = row_ptr[n + 1];
    float base = ai[n * 64 + c] + c0[l * 64 + c];
    float uc = u[l * 64 + c];
    const unsigned* __restrict__ pc = packed + c;
    float d0 = 0.f, d1 = 0.f, s0 = 0.f, s1 = 0.f;
    int k = beg;
    for (; k + 8 <= end; k += 8) {
        int2 e[8]; unsigned p[8];
        #pragma unroll
        for (int q = 0; q < 8; q++) e[q] = er[k + q];
        #pragma unroll
        for (int q = 0; q < 8; q++) p[q] = pc[(size_t)e[q].x << 6];
        #pragma unroll
        for (int q = 0; q < 8; q++) {
            float a = fmaf(__int_as_float(e[q].y), uc, base + __uint_as_float(p[q] & 0xffff0000u));
            a = fmaxf(a, NEG * a);
            float xx = __expf(a);
            if (q & 1) { d1 += xx; s1 = fmaf(xx, __uint_as_float(p[q] << 16), s1); }
            else       { d0 += xx; s0 = fmaf(xx, __uint_as_float(p[q] << 16), s0); }
        }
    }
    for (; k + 4 <= end; k += 4) {
        int2 e[4]; unsigned p[4];
        #pragma unroll
        for (int q = 0; q < 4; q++) e[q] = er[k + q];
        #pragma unroll
        for (int q = 0; q < 4; q++) p[q] = pc[(size_t)e[q].x << 6];
        #pragma unroll
        for (int q = 0; q < 4; q++) {
            float a = fmaf(__int_as_float(e[q].y), uc, base + __uint_as_float(p[q] & 0xffff0000u));
            a = fmaxf(a, NEG * a);
            float xx = __expf(a);
            if (q & 1) { d1 += xx; s1 = fmaf(xx, __uint_as_float(p[q] << 16), s1); }
            else       { d0 += xx; s0 = fmaf(xx, __uint_as_float(p[q] << 16), s0); }
        }
    }
    for (; k < end; k++) {
        int2 e0 = er[k];
        unsigned p0 = pc[(size_t)e0.x << 6];
        float a0 = fmaf(__int_as_float(e0.y), uc, base + __uint_as_float(p0 & 0xffff0000u));
        a0 = fmaxf(a0, NEG * a0);
        float x0 = __expf(a0);
        d0 += x0;
        s0 = fmaf(x0, __uint_as_float(p0 << 16), s0);
    }
    hout[n * 64 + c] = (s0 + s1) / (d0 + d1 + 1e-16f);
}

// ---------------- launch ----------------
extern "C" void kernel_launch(void* const* d_in, const int* in_sizes, int n_in,
                              void* d_out, int out_size, void* d_ws, size_t ws_size,
                              hipStream_t stream)
{
    const float* x    = (const float*)d_in[0];
    const float* ea   = (const float*)d_in[1];
    const int*   ei   = (const int*)d_in[2];
    const float* fnw  = (const float*)d_in[3];
    const float* fnb  = (const float*)d_in[4];
    const float* few  = (const float*)d_in[5];
    const float* feb  = (const float*)d_in[6];
    const float* gmm  = (const float*)d_in[7];
    const float* beta = (const float*)d_in[8];
    const float* fcw  = (const float*)d_in[9];
    const float* fcb  = (const float*)d_in[10];
    const float* aw   = (const float*)d_in[11];
    const float* ab   = (const float*)d_in[12];
    float* out = (float*)d_out;

    char* ws = (char*)d_ws;
    size_t off = 0;
    auto alloc = [&](size_t bytes) -> void* {
        void* p = ws + off;
        off += (bytes + 255) / 256 * 256;
        return p;
    };
    float*    h       = (float*)   alloc((size_t)NN * 64 * 4);
    float*    ai      = (float*)   alloc((size_t)NN * 64 * 4);
    unsigned* packed  = (unsigned*)alloc((size_t)NN * 64 * 4);
    int2*     er      = (int2*)    alloc((size_t)NE * 8);
    int2*     brec    = (int2*)    alloc((size_t)NE * 8);
    int*      row_ptr = (int*)     alloc((size_t)(NN + 1) * 4);
    int*      counts  = (int*)     alloc((size_t)NB * NWG * 4);
    int*      bbase   = (int*)     alloc((NB + 1) * 4);
    float*    mom     = (float*)   alloc(12 * 4);
    float*    bscale  = (float*)   alloc(64 * 4);
    float*    uvec    = (float*)   alloc(192 * 4);
    float*    c0vec   = (float*)   alloc(192 * 4);
    float*    feff    = (float*)   alloc(192 * 4);
    unsigned short* wt = (unsigned short*)alloc((size_t)LAYERS * 192 * 64 * 2);

    hipMemsetAsync(mom, 0, 12 * 4, stream);

    // analytic BN + derived weights (BN folded into layer-0 weights)
    k_moments<<<MOMB, 256, 0, stream>>>(x, mom);
    k_params<<<1, 256, 0, stream>>>(mom, fnw, fnb, gmm, beta, few, feb, aw, ab, fcb, fcw,
                                    bscale, uvec, c0vec, feff);
    k_prep<<<dim3(192, LAYERS), 64, 0, stream>>>(fcw, aw, bscale, wt);

    // CSR build via multisplit
    k_bcount<<<NWG, 256, 0, stream>>>(ei, counts);
    k_bscan<<<1, 256, 0, stream>>>(counts, bbase, row_ptr);
    k_bwrite<<<NWG, 256, 0, stream>>>(ei, ea, counts, brec);
    k_csr<<<NB, 256, 0, stream>>>(brec, bbase, row_ptr, er);

    // 3 GAT layers
    for (int l = 0; l < LAYERS; l++) {
        if (l == 0)
            k_tf<true><<<(NN + 63) / 64, 256, 0, stream>>>(h, x, fnw, fnb,
                wt, feff, ai, packed);
        else
            k_tf<false><<<(NN + 63) / 64, 256, 0, stream>>>(h, x, fnw, fnb,
                wt + (size_t)l * 192 * 64, feff + l * 64, ai, packed);
        float* ho = (l == LAYERS - 1) ? out : h;
        k_edge<<<NN / 4, 256, 0, stream>>>(packed, ai, row_ptr, er,
                                           uvec, c0vec, ho, l);
    }
    (void)in_sizes; (void)n_in; (void)out_size; (void)ws_size;
}

// Round 9
// 460.724 us; speedup vs baseline: 2.8581x; 1.0632x over previous
//
#include <hip/hip_runtime.h>
#include <math.h>

#define NN 100000
#define NE 1600000
#define LAYERS 3
#define NEG 0.2f
#define BN_EPS 1e-5f

#define NB 196            // buckets = ceil(NN / 512)
#define NWG 128           // multisplit workgroups
#define CHUNK 12500       // NE / NWG exactly
#define MOMB 304          // moments blocks
#define TFB 1563          // tf blocks = ceil(NN/64)

typedef __attribute__((ext_vector_type(8))) short bf16x8;
typedef __attribute__((ext_vector_type(4))) float f32x4;

__device__ __forceinline__ unsigned f2bf(float x) {   // fp32 -> bf16 bits, RNE
    unsigned u = __float_as_uint(x);
    return (u + 0x7fffu + ((u >> 16) & 1u)) >> 16;
}

// ================= fused front: bucket histogram (blocks 0..NWG) + x moments =================
__global__ __launch_bounds__(256) void k_front(const int* __restrict__ ei,
    int* __restrict__ counts, const float* __restrict__ x, float* __restrict__ mom)
{
    int t = threadIdx.x;
    if (blockIdx.x < NWG) {
        __shared__ int hist[NB];
        int wg = blockIdx.x;
        if (t < NB) hist[t] = 0;
        __syncthreads();
        int base = wg * CHUNK;
        for (int i = t; i < CHUNK; i += 256)
            atomicAdd(&hist[ei[NE + base + i] >> 9], 1);
        __syncthreads();
        if (t < NB) counts[t * NWG + wg] = hist[t];
    } else {
        int mb = blockIdx.x - NWG;
        float s0=0,s1=0,s2=0,m00=0,m01=0,m02=0,m11=0,m12=0,m22=0;
        for (int n = mb * 256 + t; n < NN; n += MOMB * 256) {
            float a = x[n*3], b = x[n*3+1], c = x[n*3+2];
            s0 += a; s1 += b; s2 += c;
            m00 = fmaf(a,a,m00); m01 = fmaf(a,b,m01); m02 = fmaf(a,c,m02);
            m11 = fmaf(b,b,m11); m12 = fmaf(b,c,m12); m22 = fmaf(c,c,m22);
        }
        #pragma unroll
        for (int off = 32; off; off >>= 1) {
            s0 += __shfl_xor(s0, off); s1 += __shfl_xor(s1, off); s2 += __shfl_xor(s2, off);
            m00 += __shfl_xor(m00, off); m01 += __shfl_xor(m01, off); m02 += __shfl_xor(m02, off);
            m11 += __shfl_xor(m11, off); m12 += __shfl_xor(m12, off); m22 += __shfl_xor(m22, off);
        }
        __shared__ float red[4][9];
        int wave = t >> 6, lane = t & 63;
        if (lane == 0) {
            red[wave][0]=s0; red[wave][1]=s1; red[wave][2]=s2;
            red[wave][3]=m00; red[wave][4]=m01; red[wave][5]=m02;
            red[wave][6]=m11; red[wave][7]=m12; red[wave][8]=m22;
        }
        __syncthreads();
        if (t < 9) {
            float v = red[0][t] + red[1][t] + red[2][t] + red[3][t];
            atomicAdd(&mom[t], v);
        }
    }
}

// analytic BN scale for channel k from x-moments
__device__ __forceinline__ float bn_scale_of(const float* __restrict__ mom,
    const float* __restrict__ fnw, const float* __restrict__ fnb,
    const float* __restrict__ gamma, int k)
{
    float w0 = fnw[k], w1 = fnw[64 + k], w2 = fnw[128 + k], bc = fnb[k];
    float dot  = mom[0]*w0 + mom[1]*w1 + mom[2]*w2;
    float quad = mom[3]*w0*w0 + 2.f*mom[4]*w0*w1 + 2.f*mom[5]*w0*w2
               + mom[6]*w1*w1 + 2.f*mom[7]*w1*w2 + mom[8]*w2*w2;
    float mean = dot * (1.0f / NN) + bc;
    float eh2  = quad * (1.0f / NN) + 2.f * bc * dot * (1.0f / NN) + bc * bc;
    float var  = eh2 - mean * mean;
    return gamma[k] * rsqrtf(var + BN_EPS);
}

// ================= fused mid: params (block 0) + bscan (block 1) + prep (blocks 2+) =================
__global__ __launch_bounds__(256) void k_mid(const float* __restrict__ mom,
    const float* __restrict__ fnw, const float* __restrict__ fnb,
    const float* __restrict__ gamma, const float* __restrict__ beta,
    const float* __restrict__ few, const float* __restrict__ feb,
    const float* __restrict__ attn_w, const float* __restrict__ attn_b,
    const float* __restrict__ fcb, const float* __restrict__ fcw,
    int* __restrict__ counts, int* __restrict__ bbase, int* __restrict__ row_ptr,
    float* __restrict__ u, float* __restrict__ c0, float* __restrict__ feff,
    unsigned short* __restrict__ wt)
{
    int t = threadIdx.x;
    if (blockIdx.x == 0) {
        // ---- params ----
        __shared__ float ssh[64], sfe[3][64];
        if (t < 64) {
            float w0 = fnw[t], w1 = fnw[64 + t], w2 = fnw[128 + t], bc = fnb[t];
            float dot  = mom[0]*w0 + mom[1]*w1 + mom[2]*w2;
            float quad = mom[3]*w0*w0 + 2.f*mom[4]*w0*w1 + 2.f*mom[5]*w0*w2
                       + mom[6]*w1*w1 + 2.f*mom[7]*w1*w2 + mom[8]*w2*w2;
            float mean = dot * (1.0f / NN) + bc;
            float eh2  = quad * (1.0f / NN) + 2.f * bc * dot * (1.0f / NN) + bc * bc;
            float var  = eh2 - mean * mean;
            float sc   = gamma[t] * rsqrtf(var + BN_EPS);
            ssh[t] = beta[t] - mean * sc;
        }
        __syncthreads();
        if (t < 64) {
            float v = 0.f;                              // v = sh @ W0_0
            for (int k = 0; k < 64; k++) v = fmaf(ssh[k], fcw[k * 64 + t], v);
            sfe[0][t] = fcb[t] + v;
            sfe[1][t] = fcb[64 + t];
            sfe[2][t] = fcb[128 + t];
        }
        __syncthreads();
        if (t < 192) {
            int l = t >> 6, c = t & 63;
            const float* AW = attn_w + l * 144 * 64;
            float uu = 0.f, cc = 0.f;
            for (int j = 0; j < 16; j++) {
                float wv = AW[(128 + j) * 64 + c];
                uu = fmaf(few[j], wv, uu);
                cc = fmaf(feb[j], wv, cc);
            }
            float bi = 0.f;                             // fcb_eff @ (Wi + Wj)
            for (int tt = 0; tt < 64; tt++)
                bi = fmaf(sfe[l][tt], AW[tt * 64 + c] + AW[(64 + tt) * 64 + c], bi);
            u[t]    = uu;
            c0[t]   = cc + attn_b[t] + bi;
            feff[t] = sfe[l][c];
        }
    } else if (blockIdx.x == 1) {
        // ---- bscan ----
        __shared__ int s_tot[256];
        int tot = 0;
        if (t < NB)
            for (int w = 0; w < NWG; w++) tot += counts[t * NWG + w];
        s_tot[t] = tot;
        __syncthreads();
        for (int off = 1; off < 256; off <<= 1) {
            int v = (t >= off) ? s_tot[t - off] : 0;
            __syncthreads();
            s_tot[t] += v;
            __syncthreads();
        }
        int excl = s_tot[t] - tot;
        if (t < NB) {
            bbase[t] = excl;
            int run = excl;
            for (int w = 0; w < NWG; w++) {
                int c = counts[t * NWG + w];
                counts[t * NWG + w] = run;
                run += c;
            }
            if (t == NB - 1) {
                bbase[NB] = run;          // == NE
                row_ptr[NN] = run;
            }
        }
    } else {
        // ---- prep: 4 tasks of 64 threads per block ----
        int task = (blockIdx.x - 2) * 4 + (t >> 6);
        int k = t & 63;
        int l = task / 192, g = task - l * 192;
        const float* W0 = fcw + l * 4096;
        float scale = (l == 0) ? bn_scale_of(mom, fnw, fnb, gamma, k) : 1.0f;
        float v;
        if (g < 64) {
            v = W0[k * 64 + g] * scale;
        } else {
            int c = g & 63;
            const float* Wx = attn_w + l * 144 * 64 + (g < 128 ? 0 : 4096);
            float s = 0.f;
            for (int tt = 0; tt < 64; tt++) s = fmaf(W0[k * 64 + tt], Wx[tt * 64 + c], s);
            v = s * scale;
        }
        wt[(l * 192 + g) * 64 + k] = (unsigned short)f2bf(v);
    }
}

// ================= tf core: MFMA [hl | ai | aj] given A-fragments =================
__device__ __forceinline__ void tf_core(const bf16x8* a, const unsigned short* __restrict__ wt_l,
    const float* __restrict__ feff_l, const float* __restrict__ c0_l,
    float* __restrict__ ai, unsigned* __restrict__ packed, int n0, int r16, int quad)
{
    f32x4 acc[12];
    #pragma unroll
    for (int i = 0; i < 12; i++) acc[i] = (f32x4){0.f, 0.f, 0.f, 0.f};
    const unsigned short* wb = wt_l + (size_t)r16 * 64 + quad * 8;
    #pragma unroll
    for (int cb = 0; cb < 12; cb++) {
        bf16x8 b0 = *(const bf16x8*)(wb + cb * 1024);
        bf16x8 b1 = *(const bf16x8*)(wb + cb * 1024 + 32);
        acc[cb] = __builtin_amdgcn_mfma_f32_16x16x32_bf16(a[0], b0, acc[cb], 0, 0, 0);
        acc[cb] = __builtin_amdgcn_mfma_f32_16x16x32_bf16(a[1], b1, acc[cb], 0, 0, 0);
    }
    #pragma unroll
    for (int r = 0; r < 4; r++) {
        int nd = n0 + quad * 4 + r;
        if (nd < NN) {
            size_t base = (size_t)nd * 64 + r16;
            #pragma unroll
            for (int cq = 0; cq < 4; cq++) {
                float hlv = acc[cq][r] + feff_l[cq * 16 + r16];
                float aiv = acc[4 + cq][r] + c0_l[cq * 16 + r16];   // c0 folded in
                float ajv = acc[8 + cq][r];
                ai[base + cq * 16]     = aiv;
                packed[base + cq * 16] = f2bf(hlv) | (f2bf(ajv) << 16);
            }
        }
    }
}

// ================= fused l3: bwrite (blocks 0..NWG) + tf layer 0 =================
__global__ __launch_bounds__(256) void k_l3(const int* __restrict__ ei,
    const float* __restrict__ ea, const int* __restrict__ counts, int2* __restrict__ brec,
    const float* __restrict__ xin, const float* __restrict__ fnw, const float* __restrict__ fnb,
    const unsigned short* __restrict__ wt, const float* __restrict__ feff,
    const float* __restrict__ c0v, float* __restrict__ ai, unsigned* __restrict__ packed)
{
    int t = threadIdx.x;
    if (blockIdx.x < NWG) {
        __shared__ int off[NB];
        int wg = blockIdx.x;
        if (t < NB) off[t] = counts[t * NWG + wg];
        __syncthreads();
        int base = wg * CHUNK;
        for (int i = t; i < CHUNK; i += 256) {
            int k = base + i;
            int s = ei[k], d = ei[NE + k];
            int b = d >> 9;
            int j = atomicAdd(&off[b], 1);
            brec[j] = make_int2(((d & 511) << 17) | s, __float_as_int(ea[k]));
        }
    } else {
        int bid = blockIdx.x - NWG;
        int wv = t >> 6, l = t & 63;
        int r16 = l & 15, quad = l >> 4;
        int n0 = bid * 64 + wv * 16;
        int na = n0 + r16; if (na >= NN) na = NN - 1;
        float x0 = xin[na*3], x1 = xin[na*3+1], x2 = xin[na*3+2];
        bf16x8 a[2];
        #pragma unroll
        for (int ks = 0; ks < 2; ks++) {
            bf16x8 tt;
            #pragma unroll
            for (int e = 0; e < 8; e++) {
                int c = quad * 8 + ks * 32 + e;
                float v = fmaf(x0, fnw[c], fmaf(x1, fnw[64 + c], fmaf(x2, fnw[128 + c], fnb[c])));
                tt[e] = (short)f2bf(v);
            }
            a[ks] = tt;
        }
        tf_core(a, wt, feff, c0v, ai, packed, n0, r16, quad);
    }
}

// ================= csr finalize (one WG per bucket) =================
__global__ __launch_bounds__(256) void k_csr(const int2* __restrict__ brec,
    const int* __restrict__ bbase, int* __restrict__ row_ptr, int2* __restrict__ er)
{
    __shared__ int s_cnt[512], s_excl[512], s_ts[256];
    int t = threadIdx.x, b = blockIdx.x;
    int beg = bbase[b], end = bbase[b + 1];
    s_cnt[t] = 0; s_cnt[t + 256] = 0;
    __syncthreads();
    for (int i = beg + t; i < end; i += 256)
        atomicAdd(&s_cnt[brec[i].x >> 17], 1);
    __syncthreads();
    int a0 = s_cnt[2 * t], a1 = s_cnt[2 * t + 1];
    int ts = a0 + a1;
    s_ts[t] = ts;
    __syncthreads();
    for (int off = 1; off < 256; off <<= 1) {
        int v = (t >= off) ? s_ts[t - off] : 0;
        __syncthreads();
        s_ts[t] += v;
        __syncthreads();
    }
    int et = s_ts[t] - ts;
    s_excl[2 * t] = et; s_excl[2 * t + 1] = et + a0;
    s_cnt[t] = 0; s_cnt[t + 256] = 0;
    __syncthreads();
    #pragma unroll
    for (int q = 0; q < 2; q++) {
        int dl = t + q * 256;
        int n = b * 512 + dl;
        if (n < NN) row_ptr[n] = beg + s_excl[dl];
    }
    for (int i = beg + t; i < end; i += 256) {
        int2 r = brec[i];
        int dl = r.x >> 17;
        int pos = atomicAdd(&s_cnt[dl], 1);
        er[beg + s_excl[dl] + pos] = make_int2(r.x & 0x1FFFF, r.y);
    }
}

// ================= tf layers 1,2 (reads h) =================
__global__ __launch_bounds__(256) void k_tf(const float* __restrict__ h,
    const unsigned short* __restrict__ wt_l, const float* __restrict__ feff_l,
    const float* __restrict__ c0_l, float* __restrict__ ai, unsigned* __restrict__ packed)
{
    int t = threadIdx.x;
    int wv = t >> 6, l = t & 63;
    int r16 = l & 15, quad = l >> 4;
    int n0 = blockIdx.x * 64 + wv * 16;
    int na = n0 + r16; if (na >= NN) na = NN - 1;
    const float* hp = h + (size_t)na * 64 + quad * 8;
    bf16x8 a[2];
    #pragma unroll
    for (int ks = 0; ks < 2; ks++) {
        f32x4 lo = *(const f32x4*)(hp + ks * 32);
        f32x4 hi = *(const f32x4*)(hp + ks * 32 + 4);
        bf16x8 tt;
        tt[0] = (short)f2bf(lo[0]); tt[1] = (short)f2bf(lo[1]);
        tt[2] = (short)f2bf(lo[2]); tt[3] = (short)f2bf(lo[3]);
        tt[4] = (short)f2bf(hi[0]); tt[5] = (short)f2bf(hi[1]);
        tt[6] = (short)f2bf(hi[2]); tt[7] = (short)f2bf(hi[3]);
        a[ks] = tt;
    }
    tf_core(a, wt_l, feff_l, c0_l, ai, packed, n0, r16, quad);
}

// ================= fused softmax-attention aggregate, unroll-8 =================
__global__ __launch_bounds__(256) void k_edge(const unsigned* __restrict__ packed,
    const float* __restrict__ ai, const int* __restrict__ row_ptr,
    const int2* __restrict__ er, const float* __restrict__ u_l,
    float* __restrict__ hout)
{
    int w = threadIdx.x >> 6, c = threadIdx.x & 63;
    int n = blockIdx.x * 4 + w;                   // grid exact NN/4
    int beg = row_ptr[n], end = row_ptr[n + 1];
    float base = ai[n * 64 + c];                  // c0 already folded in
    float uc = u_l[c];
    const unsigned* __restrict__ pc = packed + c;
    float d0 = 0.f, d1 = 0.f, s0 = 0.f, s1 = 0.f;
    int k = beg;
    for (; k + 8 <= end; k += 8) {
        int2 e[8]; unsigned p[8];
        #pragma unroll
        for (int q = 0; q < 8; q++) e[q] = er[k + q];
        #pragma unroll
        for (int q = 0; q < 8; q++) p[q] = pc[(size_t)e[q].x << 6];
        #pragma unroll
        for (int q = 0; q < 8; q++) {
            float a = fmaf(__int_as_float(e[q].y), uc, base + __uint_as_float(p[q] & 0xffff0000u));
            a = fmaxf(a, NEG * a);
            float xx = __expf(a);
            if (q & 1) { d1 += xx; s1 = fmaf(xx, __uint_as_float(p[q] << 16), s1); }
            else       { d0 += xx; s0 = fmaf(xx, __uint_as_float(p[q] << 16), s0); }
        }
    }
    for (; k + 4 <= end; k += 4) {
        int2 e[4]; unsigned p[4];
        #pragma unroll
        for (int q = 0; q < 4; q++) e[q] = er[k + q];
        #pragma unroll
        for (int q = 0; q < 4; q++) p[q] = pc[(size_t)e[q].x << 6];
        #pragma unroll
        for (int q = 0; q < 4; q++) {
            float a = fmaf(__int_as_float(e[q].y), uc, base + __uint_as_float(p[q] & 0xffff0000u));
            a = fmaxf(a, NEG * a);
            float xx = __expf(a);
            if (q & 1) { d1 += xx; s1 = fmaf(xx, __uint_as_float(p[q] << 16), s1); }
            else       { d0 += xx; s0 = fmaf(xx, __uint_as_float(p[q] << 16), s0); }
        }
    }
    for (; k < end; k++) {
        int2 e0 = er[k];
        unsigned p0 = pc[(size_t)e0.x << 6];
        float a0 = fmaf(__int_as_float(e0.y), uc, base + __uint_as_float(p0 & 0xffff0000u));
        a0 = fmaxf(a0, NEG * a0);
        float x0 = __expf(a0);
        d0 += x0;
        s0 = fmaf(x0, __uint_as_float(p0 << 16), s0);
    }
    hout[n * 64 + c] = (s0 + s1) / (d0 + d1 + 1e-16f);
}

// ---------------- launch ----------------
extern "C" void kernel_launch(void* const* d_in, const int* in_sizes, int n_in,
                              void* d_out, int out_size, void* d_ws, size_t ws_size,
                              hipStream_t stream)
{
    const float* x    = (const float*)d_in[0];
    const float* ea   = (const float*)d_in[1];
    const int*   ei   = (const int*)d_in[2];
    const float* fnw  = (const float*)d_in[3];
    const float* fnb  = (const float*)d_in[4];
    const float* few  = (const float*)d_in[5];
    const float* feb  = (const float*)d_in[6];
    const float* gmm  = (const float*)d_in[7];
    const float* beta = (const float*)d_in[8];
    const float* fcw  = (const float*)d_in[9];
    const float* fcb  = (const float*)d_in[10];
    const float* aw   = (const float*)d_in[11];
    const float* ab   = (const float*)d_in[12];
    float* out = (float*)d_out;

    char* ws = (char*)d_ws;
    size_t off = 0;
    auto alloc = [&](size_t bytes) -> void* {
        void* p = ws + off;
        off += (bytes + 255) / 256 * 256;
        return p;
    };
    float*    h       = (float*)   alloc((size_t)NN * 64 * 4);
    float*    ai      = (float*)   alloc((size_t)NN * 64 * 4);
    unsigned* packed  = (unsigned*)alloc((size_t)NN * 64 * 4);
    int2*     er      = (int2*)    alloc((size_t)NE * 8);
    int2*     brec    = (int2*)    alloc((size_t)NE * 8);
    int*      row_ptr = (int*)     alloc((size_t)(NN + 1) * 4);
    int*      counts  = (int*)     alloc((size_t)NB * NWG * 4);
    int*      bbase   = (int*)     alloc((NB + 1) * 4);
    float*    mom     = (float*)   alloc(12 * 4);
    float*    uvec    = (float*)   alloc(192 * 4);
    float*    c0vec   = (float*)   alloc(192 * 4);
    float*    feff    = (float*)   alloc(192 * 4);
    unsigned short* wt = (unsigned short*)alloc((size_t)LAYERS * 192 * 64 * 2);

    (void)hipMemsetAsync(mom, 0, 12 * 4, stream);

    // L1: bucket histogram + x moments
    k_front<<<NWG + MOMB, 256, 0, stream>>>(ei, counts, x, mom);
    // L2: params + bucket scan + weight prep
    k_mid<<<2 + 144, 256, 0, stream>>>(mom, fnw, fnb, gmm, beta, few, feb, aw, ab,
                                       fcb, fcw, counts, bbase, row_ptr,
                                       uvec, c0vec, feff, wt);
    // L3: bucket write + tf layer 0
    k_l3<<<NWG + TFB, 256, 0, stream>>>(ei, ea, counts, brec, x, fnw, fnb,
                                        wt, feff, c0vec, ai, packed);
    // L4: csr finalize
    k_csr<<<NB, 256, 0, stream>>>(brec, bbase, row_ptr, er);
    // L5..: edge / tf chain
    k_edge<<<NN / 4, 256, 0, stream>>>(packed, ai, row_ptr, er, uvec, h);
    k_tf<<<TFB, 256, 0, stream>>>(h, wt + (size_t)192 * 64, feff + 64, c0vec + 64, ai, packed);
    k_edge<<<NN / 4, 256, 0, stream>>>(packed, ai, row_ptr, er, uvec + 64, h);
    k_tf<<<TFB, 256, 0, stream>>>(h, wt + (size_t)2 * 192 * 64, feff + 128, c0vec + 128, ai, packed);
    k_edge<<<NN / 4, 256, 0, stream>>>(packed, ai, row_ptr, er, uvec + 128, out);
    (void)in_sizes; (void)n_in; (void)out_size; (void)ws_size;
}

// Round 10
// 441.892 us; speedup vs baseline: 2.9799x; 1.0426x over previous
//
#include <hip/hip_runtime.h>
#include <math.h>

#define NN 100000
#define NE 1600000
#define LAYERS 3
#define NEG 0.2f
#define BN_EPS 1e-5f

#define NB 196            // buckets = ceil(NN / 512)
#define NWG 512           // multisplit workgroups
#define CHUNK 3125        // NE / NWG exactly
#define MOMB 304          // moments blocks
#define TFB 1563          // tf blocks = ceil(NN/64)

typedef __attribute__((ext_vector_type(8))) short bf16x8;
typedef __attribute__((ext_vector_type(4))) float f32x4;

__device__ __forceinline__ unsigned f2bf(float x) {   // fp32 -> bf16 bits, RNE
    unsigned u = __float_as_uint(x);
    return (u + 0x7fffu + ((u >> 16) & 1u)) >> 16;
}

// ================= fused front: bucket histogram (blocks 0..NWG) + x moments =================
__global__ __launch_bounds__(256) void k_front(const int* __restrict__ ei,
    int* __restrict__ counts, const float* __restrict__ x, float* __restrict__ mom)
{
    int t = threadIdx.x;
    if (blockIdx.x < NWG) {
        __shared__ int hist[NB];
        int wg = blockIdx.x;
        if (t < NB) hist[t] = 0;
        __syncthreads();
        int base = wg * CHUNK;
        for (int i = t; i < CHUNK; i += 256)
            atomicAdd(&hist[ei[NE + base + i] >> 9], 1);
        __syncthreads();
        if (t < NB) counts[wg * NB + t] = hist[t];      // [w][bucket], coalesced
    } else {
        int mb = blockIdx.x - NWG;
        float s0=0,s1=0,s2=0,m00=0,m01=0,m02=0,m11=0,m12=0,m22=0;
        for (int n = mb * 256 + t; n < NN; n += MOMB * 256) {
            float a = x[n*3], b = x[n*3+1], c = x[n*3+2];
            s0 += a; s1 += b; s2 += c;
            m00 = fmaf(a,a,m00); m01 = fmaf(a,b,m01); m02 = fmaf(a,c,m02);
            m11 = fmaf(b,b,m11); m12 = fmaf(b,c,m12); m22 = fmaf(c,c,m22);
        }
        #pragma unroll
        for (int off = 32; off; off >>= 1) {
            s0 += __shfl_xor(s0, off); s1 += __shfl_xor(s1, off); s2 += __shfl_xor(s2, off);
            m00 += __shfl_xor(m00, off); m01 += __shfl_xor(m01, off); m02 += __shfl_xor(m02, off);
            m11 += __shfl_xor(m11, off); m12 += __shfl_xor(m12, off); m22 += __shfl_xor(m22, off);
        }
        __shared__ float red[4][9];
        int wave = t >> 6, lane = t & 63;
        if (lane == 0) {
            red[wave][0]=s0; red[wave][1]=s1; red[wave][2]=s2;
            red[wave][3]=m00; red[wave][4]=m01; red[wave][5]=m02;
            red[wave][6]=m11; red[wave][7]=m12; red[wave][8]=m22;
        }
        __syncthreads();
        if (t < 9) {
            float v = red[0][t] + red[1][t] + red[2][t] + red[3][t];
            atomicAdd(&mom[t], v);
        }
    }
}

// analytic BN scale for channel k from x-moments
__device__ __forceinline__ float bn_scale_of(const float* __restrict__ mom,
    const float* __restrict__ fnw, const float* __restrict__ fnb,
    const float* __restrict__ gamma, int k)
{
    float w0 = fnw[k], w1 = fnw[64 + k], w2 = fnw[128 + k], bc = fnb[k];
    float dot  = mom[0]*w0 + mom[1]*w1 + mom[2]*w2;
    float quad = mom[3]*w0*w0 + 2.f*mom[4]*w0*w1 + 2.f*mom[5]*w0*w2
               + mom[6]*w1*w1 + 2.f*mom[7]*w1*w2 + mom[8]*w2*w2;
    float mean = dot * (1.0f / NN) + bc;
    float eh2  = quad * (1.0f / NN) + 2.f * bc * dot * (1.0f / NN) + bc * bc;
    float var  = eh2 - mean * mean;
    return gamma[k] * rsqrtf(var + BN_EPS);
}

// ================= fused mid: params (block 0) + bscan (block 1) + prep (blocks 2+) =================
__global__ __launch_bounds__(256) void k_mid(const float* __restrict__ mom,
    const float* __restrict__ fnw, const float* __restrict__ fnb,
    const float* __restrict__ gamma, const float* __restrict__ beta,
    const float* __restrict__ few, const float* __restrict__ feb,
    const float* __restrict__ attn_w, const float* __restrict__ attn_b,
    const float* __restrict__ fcb, const float* __restrict__ fcw,
    int* __restrict__ counts, int* __restrict__ bbase, int* __restrict__ row_ptr,
    float* __restrict__ u, float* __restrict__ c0, float* __restrict__ feff,
    unsigned short* __restrict__ wt)
{
    int t = threadIdx.x;
    if (blockIdx.x == 0) {
        // ---- params ----
        __shared__ float ssh[64], sfe[3][64];
        if (t < 64) {
            float w0 = fnw[t], w1 = fnw[64 + t], w2 = fnw[128 + t], bc = fnb[t];
            float dot  = mom[0]*w0 + mom[1]*w1 + mom[2]*w2;
            float quad = mom[3]*w0*w0 + 2.f*mom[4]*w0*w1 + 2.f*mom[5]*w0*w2
                       + mom[6]*w1*w1 + 2.f*mom[7]*w1*w2 + mom[8]*w2*w2;
            float mean = dot * (1.0f / NN) + bc;
            float eh2  = quad * (1.0f / NN) + 2.f * bc * dot * (1.0f / NN) + bc * bc;
            float var  = eh2 - mean * mean;
            float sc   = gamma[t] * rsqrtf(var + BN_EPS);
            ssh[t] = beta[t] - mean * sc;
        }
        __syncthreads();
        if (t < 64) {
            float v = 0.f;                              // v = sh @ W0_0
            for (int k = 0; k < 64; k++) v = fmaf(ssh[k], fcw[k * 64 + t], v);
            sfe[0][t] = fcb[t] + v;
            sfe[1][t] = fcb[64 + t];
            sfe[2][t] = fcb[128 + t];
        }
        __syncthreads();
        if (t < 192) {
            int l = t >> 6, c = t & 63;
            const float* AW = attn_w + l * 144 * 64;
            float uu = 0.f, cc = 0.f;
            for (int j = 0; j < 16; j++) {
                float wv = AW[(128 + j) * 64 + c];
                uu = fmaf(few[j], wv, uu);
                cc = fmaf(feb[j], wv, cc);
            }
            float bi = 0.f;                             // fcb_eff @ (Wi + Wj)
            for (int tt = 0; tt < 64; tt++)
                bi = fmaf(sfe[l][tt], AW[tt * 64 + c] + AW[(64 + tt) * 64 + c], bi);
            u[t]    = uu;
            c0[t]   = cc + attn_b[t] + bi;
            feff[t] = sfe[l][c];
        }
    } else if (blockIdx.x == 1) {
        // ---- bscan ----
        __shared__ int s_tot[256];
        int tot = 0;
        if (t < NB)
            for (int w = 0; w < NWG; w++) tot += counts[w * NB + t];
        s_tot[t] = tot;
        __syncthreads();
        for (int off = 1; off < 256; off <<= 1) {
            int v = (t >= off) ? s_tot[t - off] : 0;
            __syncthreads();
            s_tot[t] += v;
            __syncthreads();
        }
        int excl = s_tot[t] - tot;
        if (t < NB) {
            bbase[t] = excl;
            int run = excl;
            for (int w = 0; w < NWG; w++) {
                int c = counts[w * NB + t];
                counts[w * NB + t] = run;
                run += c;
            }
            if (t == NB - 1) {
                bbase[NB] = run;          // == NE
                row_ptr[NN] = run;
            }
        }
    } else {
        // ---- prep: 4 tasks of 64 threads per block ----
        int task = (blockIdx.x - 2) * 4 + (t >> 6);
        int k = t & 63;
        int l = task / 192, g = task - l * 192;
        const float* W0 = fcw + l * 4096;
        float scale = (l == 0) ? bn_scale_of(mom, fnw, fnb, gamma, k) : 1.0f;
        float v;
        if (g < 64) {
            v = W0[k * 64 + g] * scale;
        } else {
            int c = g & 63;
            const float* Wx = attn_w + l * 144 * 64 + (g < 128 ? 0 : 4096);
            float s = 0.f;
            for (int tt = 0; tt < 64; tt++) s = fmaf(W0[k * 64 + tt], Wx[tt * 64 + c], s);
            v = s * scale;
        }
        wt[(l * 192 + g) * 64 + k] = (unsigned short)f2bf(v);
    }
}

// ================= tf core: MFMA [hl | ai | aj] given A-fragments =================
__device__ __forceinline__ void tf_core(const bf16x8* a, const unsigned short* __restrict__ wt_l,
    const float* __restrict__ feff_l, const float* __restrict__ c0_l,
    float* __restrict__ ai, unsigned* __restrict__ packed, int n0, int r16, int quad)
{
    f32x4 acc[12];
    #pragma unroll
    for (int i = 0; i < 12; i++) acc[i] = (f32x4){0.f, 0.f, 0.f, 0.f};
    const unsigned short* wb = wt_l + (size_t)r16 * 64 + quad * 8;
    #pragma unroll
    for (int cb = 0; cb < 12; cb++) {
        bf16x8 b0 = *(const bf16x8*)(wb + cb * 1024);
        bf16x8 b1 = *(const bf16x8*)(wb + cb * 1024 + 32);
        acc[cb] = __builtin_amdgcn_mfma_f32_16x16x32_bf16(a[0], b0, acc[cb], 0, 0, 0);
        acc[cb] = __builtin_amdgcn_mfma_f32_16x16x32_bf16(a[1], b1, acc[cb], 0, 0, 0);
    }
    #pragma unroll
    for (int r = 0; r < 4; r++) {
        int nd = n0 + quad * 4 + r;
        if (nd < NN) {
            size_t base = (size_t)nd * 64 + r16;
            #pragma unroll
            for (int cq = 0; cq < 4; cq++) {
                float hlv = acc[cq][r] + feff_l[cq * 16 + r16];
                float aiv = acc[4 + cq][r] + c0_l[cq * 16 + r16];   // c0 folded in
                float ajv = acc[8 + cq][r];
                ai[base + cq * 16]     = aiv;
                packed[base + cq * 16] = f2bf(hlv) | (f2bf(ajv) << 16);
            }
        }
    }
}

// ================= fused l3: bwrite (blocks 0..NWG) + tf layer 0 =================
__global__ __launch_bounds__(256) void k_l3(const int* __restrict__ ei,
    const float* __restrict__ ea, const int* __restrict__ counts, int2* __restrict__ brec,
    const float* __restrict__ xin, const float* __restrict__ fnw, const float* __restrict__ fnb,
    const unsigned short* __restrict__ wt, const float* __restrict__ feff,
    const float* __restrict__ c0v, float* __restrict__ ai, unsigned* __restrict__ packed)
{
    int t = threadIdx.x;
    if (blockIdx.x < NWG) {
        __shared__ int off[NB];
        int wg = blockIdx.x;
        if (t < NB) off[t] = counts[wg * NB + t];
        __syncthreads();
        int base = wg * CHUNK;
        for (int i = t; i < CHUNK; i += 256) {
            int k = base + i;
            int s = ei[k], d = ei[NE + k];
            int b = d >> 9;
            int j = atomicAdd(&off[b], 1);
            brec[j] = make_int2(((d & 511) << 17) | s, __float_as_int(ea[k]));
        }
    } else {
        int bid = blockIdx.x - NWG;
        int wv = t >> 6, l = t & 63;
        int r16 = l & 15, quad = l >> 4;
        int n0 = bid * 64 + wv * 16;
        int na = n0 + r16; if (na >= NN) na = NN - 1;
        float x0 = xin[na*3], x1 = xin[na*3+1], x2 = xin[na*3+2];
        bf16x8 a[2];
        #pragma unroll
        for (int ks = 0; ks < 2; ks++) {
            bf16x8 tt;
            #pragma unroll
            for (int e = 0; e < 8; e++) {
                int c = quad * 8 + ks * 32 + e;
                float v = fmaf(x0, fnw[c], fmaf(x1, fnw[64 + c], fmaf(x2, fnw[128 + c], fnb[c])));
                tt[e] = (short)f2bf(v);
            }
            a[ks] = tt;
        }
        tf_core(a, wt, feff, c0v, ai, packed, n0, r16, quad);
    }
}

// ================= csr finalize (one WG per bucket) =================
__global__ __launch_bounds__(256) void k_csr(const int2* __restrict__ brec,
    const int* __restrict__ bbase, int* __restrict__ row_ptr, int2* __restrict__ er)
{
    __shared__ int s_cnt[512], s_excl[512], s_ts[256];
    int t = threadIdx.x, b = blockIdx.x;
    int beg = bbase[b], end = bbase[b + 1];
    s_cnt[t] = 0; s_cnt[t + 256] = 0;
    __syncthreads();
    for (int i = beg + t; i < end; i += 256)
        atomicAdd(&s_cnt[brec[i].x >> 17], 1);
    __syncthreads();
    int a0 = s_cnt[2 * t], a1 = s_cnt[2 * t + 1];
    int ts = a0 + a1;
    s_ts[t] = ts;
    __syncthreads();
    for (int off = 1; off < 256; off <<= 1) {
        int v = (t >= off) ? s_ts[t - off] : 0;
        __syncthreads();
        s_ts[t] += v;
        __syncthreads();
    }
    int et = s_ts[t] - ts;
    s_excl[2 * t] = et; s_excl[2 * t + 1] = et + a0;
    s_cnt[t] = 0; s_cnt[t + 256] = 0;
    __syncthreads();
    #pragma unroll
    for (int q = 0; q < 2; q++) {
        int dl = t + q * 256;
        int n = b * 512 + dl;
        if (n < NN) row_ptr[n] = beg + s_excl[dl];
    }
    for (int i = beg + t; i < end; i += 256) {
        int2 r = brec[i];
        int dl = r.x >> 17;
        int pos = atomicAdd(&s_cnt[dl], 1);
        er[beg + s_excl[dl] + pos] = make_int2(r.x & 0x1FFFF, r.y);
    }
}

// ================= tf layers 1,2 (reads h) =================
__global__ __launch_bounds__(256) void k_tf(const float* __restrict__ h,
    const unsigned short* __restrict__ wt_l, const float* __restrict__ feff_l,
    const float* __restrict__ c0_l, float* __restrict__ ai, unsigned* __restrict__ packed)
{
    int t = threadIdx.x;
    int wv = t >> 6, l = t & 63;
    int r16 = l & 15, quad = l >> 4;
    int n0 = blockIdx.x * 64 + wv * 16;
    int na = n0 + r16; if (na >= NN) na = NN - 1;
    const float* hp = h + (size_t)na * 64 + quad * 8;
    bf16x8 a[2];
    #pragma unroll
    for (int ks = 0; ks < 2; ks++) {
        f32x4 lo = *(const f32x4*)(hp + ks * 32);
        f32x4 hi = *(const f32x4*)(hp + ks * 32 + 4);
        bf16x8 tt;
        tt[0] = (short)f2bf(lo[0]); tt[1] = (short)f2bf(lo[1]);
        tt[2] = (short)f2bf(lo[2]); tt[3] = (short)f2bf(lo[3]);
        tt[4] = (short)f2bf(hi[0]); tt[5] = (short)f2bf(hi[1]);
        tt[6] = (short)f2bf(hi[2]); tt[7] = (short)f2bf(hi[3]);
        a[ks] = tt;
    }
    tf_core(a, wt_l, feff_l, c0_l, ai, packed, n0, r16, quad);
}

// ================= fused softmax-attention aggregate, unroll-16 =================
__global__ __launch_bounds__(256) void k_edge(const unsigned* __restrict__ packed,
    const float* __restrict__ ai, const int* __restrict__ row_ptr,
    const int2* __restrict__ er, const float* __restrict__ u_l,
    float* __restrict__ hout)
{
    int w = threadIdx.x >> 6, c = threadIdx.x & 63;
    int n = blockIdx.x * 4 + w;                   // grid exact NN/4
    int beg = row_ptr[n], end = row_ptr[n + 1];
    float base = ai[n * 64 + c];                  // c0 already folded in
    float uc = u_l[c];
    const unsigned* __restrict__ pc = packed + c;
    float d0 = 0.f, d1 = 0.f, s0 = 0.f, s1 = 0.f;
    int k = beg;
    for (; k + 16 <= end; k += 16) {
        int2 e[16]; unsigned p[16];
        #pragma unroll
        for (int q = 0; q < 16; q++) e[q] = er[k + q];
        #pragma unroll
        for (int q = 0; q < 16; q++) p[q] = pc[(size_t)e[q].x << 6];
        #pragma unroll
        for (int q = 0; q < 16; q++) {
            float a = fmaf(__int_as_float(e[q].y), uc, base + __uint_as_float(p[q] & 0xffff0000u));
            a = fmaxf(a, NEG * a);
            float xx = __expf(a);
            if (q & 1) { d1 += xx; s1 = fmaf(xx, __uint_as_float(p[q] << 16), s1); }
            else       { d0 += xx; s0 = fmaf(xx, __uint_as_float(p[q] << 16), s0); }
        }
    }
    for (; k + 8 <= end; k += 8) {
        int2 e[8]; unsigned p[8];
        #pragma unroll
        for (int q = 0; q < 8; q++) e[q] = er[k + q];
        #pragma unroll
        for (int q = 0; q < 8; q++) p[q] = pc[(size_t)e[q].x << 6];
        #pragma unroll
        for (int q = 0; q < 8; q++) {
            float a = fmaf(__int_as_float(e[q].y), uc, base + __uint_as_float(p[q] & 0xffff0000u));
            a = fmaxf(a, NEG * a);
            float xx = __expf(a);
            if (q & 1) { d1 += xx; s1 = fmaf(xx, __uint_as_float(p[q] << 16), s1); }
            else       { d0 += xx; s0 = fmaf(xx, __uint_as_float(p[q] << 16), s0); }
        }
    }
    for (; k + 4 <= end; k += 4) {
        int2 e[4]; unsigned p[4];
        #pragma unroll
        for (int q = 0; q < 4; q++) e[q] = er[k + q];
        #pragma unroll
        for (int q = 0; q < 4; q++) p[q] = pc[(size_t)e[q].x << 6];
        #pragma unroll
        for (int q = 0; q < 4; q++) {
            float a = fmaf(__int_as_float(e[q].y), uc, base + __uint_as_float(p[q] & 0xffff0000u));
            a = fmaxf(a, NEG * a);
            float xx = __expf(a);
            if (q & 1) { d1 += xx; s1 = fmaf(xx, __uint_as_float(p[q] << 16), s1); }
            else       { d0 += xx; s0 = fmaf(xx, __uint_as_float(p[q] << 16), s0); }
        }
    }
    for (; k < end; k++) {
        int2 e0 = er[k];
        unsigned p0 = pc[(size_t)e0.x << 6];
        float a0 = fmaf(__int_as_float(e0.y), uc, base + __uint_as_float(p0 & 0xffff0000u));
        a0 = fmaxf(a0, NEG * a0);
        float x0 = __expf(a0);
        d0 += x0;
        s0 = fmaf(x0, __uint_as_float(p0 << 16), s0);
    }
    hout[n * 64 + c] = (s0 + s1) / (d0 + d1 + 1e-16f);
}

// ---------------- launch ----------------
extern "C" void kernel_launch(void* const* d_in, const int* in_sizes, int n_in,
                              void* d_out, int out_size, void* d_ws, size_t ws_size,
                              hipStream_t stream)
{
    const float* x    = (const float*)d_in[0];
    const float* ea   = (const float*)d_in[1];
    const int*   ei   = (const int*)d_in[2];
    const float* fnw  = (const float*)d_in[3];
    const float* fnb  = (const float*)d_in[4];
    const float* few  = (const float*)d_in[5];
    const float* feb  = (const float*)d_in[6];
    const float* gmm  = (const float*)d_in[7];
    const float* beta = (const float*)d_in[8];
    const float* fcw  = (const float*)d_in[9];
    const float* fcb  = (const float*)d_in[10];
    const float* aw   = (const float*)d_in[11];
    const float* ab   = (const float*)d_in[12];
    float* out = (float*)d_out;

    char* ws = (char*)d_ws;
    size_t off = 0;
    auto alloc = [&](size_t bytes) -> void* {
        void* p = ws + off;
        off += (bytes + 255) / 256 * 256;
        return p;
    };
    float*    h       = (float*)   alloc((size_t)NN * 64 * 4);
    float*    ai      = (float*)   alloc((size_t)NN * 64 * 4);
    unsigned* packed  = (unsigned*)alloc((size_t)NN * 64 * 4);
    int2*     er      = (int2*)    alloc((size_t)NE * 8);
    int2*     brec    = (int2*)    alloc((size_t)NE * 8);
    int*      row_ptr = (int*)     alloc((size_t)(NN + 1) * 4);
    int*      counts  = (int*)     alloc((size_t)NB * NWG * 4);
    int*      bbase   = (int*)     alloc((NB + 1) * 4);
    float*    mom     = (float*)   alloc(12 * 4);
    float*    uvec    = (float*)   alloc(192 * 4);
    float*    c0vec   = (float*)   alloc(192 * 4);
    float*    feff    = (float*)   alloc(192 * 4);
    unsigned short* wt = (unsigned short*)alloc((size_t)LAYERS * 192 * 64 * 2);

    (void)hipMemsetAsync(mom, 0, 12 * 4, stream);

    // L1: bucket histogram + x moments
    k_front<<<NWG + MOMB, 256, 0, stream>>>(ei, counts, x, mom);
    // L2: params + bucket scan + weight prep
    k_mid<<<2 + 144, 256, 0, stream>>>(mom, fnw, fnb, gmm, beta, few, feb, aw, ab,
                                       fcb, fcw, counts, bbase, row_ptr,
                                       uvec, c0vec, feff, wt);
    // L3: bucket write + tf layer 0
    k_l3<<<NWG + TFB, 256, 0, stream>>>(ei, ea, counts, brec, x, fnw, fnb,
                                        wt, feff, c0vec, ai, packed);
    // L4: csr finalize
    k_csr<<<NB, 256, 0, stream>>>(brec, bbase, row_ptr, er);
    // L5..: edge / tf chain
    k_edge<<<NN / 4, 256, 0, stream>>>(packed, ai, row_ptr, er, uvec, h);
    k_tf<<<TFB, 256, 0, stream>>>(h, wt + (size_t)192 * 64, feff + 64, c0vec + 64, ai, packed);
    k_edge<<<NN / 4, 256, 0, stream>>>(packed, ai, row_ptr, er, uvec + 64, h);
    k_tf<<<TFB, 256, 0, stream>>>(h, wt + (size_t)2 * 192 * 64, feff + 128, c0vec + 128, ai, packed);
    k_edge<<<NN / 4, 256, 0, stream>>>(packed, ai, row_ptr, er, uvec + 128, out);
    (void)in_sizes; (void)n_in; (void)out_size; (void)ws_size;
}